// Round 1
// baseline (329.371 us; speedup 1.0000x reference)
//
#include <hip/hip_runtime.h>
#include <hip/hip_bf16.h>

typedef __bf16 bf16;
typedef __bf16 bf16x8 __attribute__((ext_vector_type(8)));
typedef __bf16 bf16x4 __attribute__((ext_vector_type(4)));
typedef float f32x4 __attribute__((ext_vector_type(4)));

#define EMBED 1024
#define NH 16
#define HD 64
#define BATCH 2
#define SEQ 2048
#define MTOK 4096

static __device__ __forceinline__ f32x4 mfma16(bf16x8 a, bf16x8 b, f32x4 c) {
  return __builtin_amdgcn_mfma_f32_16x16x32_bf16(a, b, c, 0, 0, 0);
}

static __device__ __forceinline__ void gld_lds16(const bf16* g, bf16* l) {
  __builtin_amdgcn_global_load_lds(
      (const __attribute__((address_space(1))) void*)g,
      (__attribute__((address_space(3))) void*)l, 16, 0, 0);
}

// ---------------- prep: x -> bf16 ----------------
__global__ __launch_bounds__(256) void cvt_x_kernel(const float* __restrict__ x,
                                                    bf16* __restrict__ xb, int n4) {
  int i = blockIdx.x * 256 + threadIdx.x;
  int stride = gridDim.x * 256;
  for (; i < n4; i += stride) {
    f32x4 v = ((const f32x4*)x)[i];
    bf16x4 o;
    o[0] = (bf16)v[0]; o[1] = (bf16)v[1]; o[2] = (bf16)v[2]; o[3] = (bf16)v[3];
    ((bf16x4*)xb)[i] = o;
  }
}

// ---------------- prep: W [K][N] fp32 -> Wt [N][K] bf16 ----------------
__global__ __launch_bounds__(256) void transpose_wt_kernel(const float* __restrict__ W,
                                                           bf16* __restrict__ Wt) {
  __shared__ float tile[64][65];
  const int bc = blockIdx.x * 64;  // n base
  const int br = blockIdx.y * 64;  // k base
  const int tid = threadIdx.x;
#pragma unroll
  for (int j = 0; j < 16; j++) {
    int idx = j * 256 + tid;
    int r = idx >> 6, c = idx & 63;
    tile[r][c] = W[(size_t)(br + r) * EMBED + bc + c];
  }
  __syncthreads();
#pragma unroll
  for (int j = 0; j < 16; j++) {
    int idx = j * 256 + tid;
    int r = idx >> 6, c = idx & 63;
    Wt[(size_t)(bc + r) * EMBED + br + c] = (bf16)tile[c][r];
  }
}

// ---------------- prep: W_q_eff^T = (q_w @ blockdiag(E'))^T, bf16 ----------------
// E'[h][d][e] = ent[h][d][e] + (d==e) * cos(phase[h][d])^2 / 8
__global__ __launch_bounds__(256) void weff_kernel(const float* __restrict__ qw,
                                                   const float* __restrict__ ent,
                                                   const float* __restrict__ phase,
                                                   bf16* __restrict__ WtQ) {
  __shared__ float qt[64][65];
  __shared__ float et[64][65];
  const int h = blockIdx.x;
  const int ibase = blockIdx.y * 64;
  const int tid = threadIdx.x;
#pragma unroll
  for (int j = 0; j < 16; j++) {
    int idx = j * 256 + tid;
    int i = idx >> 6, d = idx & 63;
    qt[i][d] = qw[(size_t)(ibase + i) * EMBED + h * HD + d];
  }
#pragma unroll
  for (int j = 0; j < 16; j++) {
    int idx = j * 256 + tid;
    int d = idx >> 6, e = idx & 63;
    float v = ent[((size_t)h * HD + d) * HD + e];
    if (d == e) { float cp = cosf(phase[h * HD + d]); v += cp * cp * 0.125f; }
    et[d][e] = v;
  }
  __syncthreads();
  const int i = tid & 63;
  const int e0 = (tid >> 6) * 16;
  float s[16];
#pragma unroll
  for (int ee = 0; ee < 16; ee++) s[ee] = 0.f;
  for (int d = 0; d < 64; d++) {
    float qv = qt[i][d];
#pragma unroll
    for (int ee = 0; ee < 16; ee++) s[ee] += qv * et[d][e0 + ee];
  }
#pragma unroll
  for (int ee = 0; ee < 16; ee++)
    WtQ[(size_t)(h * HD + e0 + ee) * EMBED + ibase + i] = (bf16)s[ee];
}

__global__ void beff_kernel(const float* __restrict__ qb, const float* __restrict__ ent,
                            const float* __restrict__ phase, float* __restrict__ beff) {
  const int h = blockIdx.x;
  const int e = threadIdx.x;  // 64
  float s = 0.f;
  for (int d = 0; d < 64; d++) {
    float v = ent[((size_t)h * HD + d) * HD + e];
    if (d == e) { float cp = cosf(phase[h * HD + d]); v += cp * cp * 0.125f; }
    s += qb[h * HD + d] * v;
  }
  beff[h * HD + e] = s;
}

// ---------------- GEMM: A[M][1024] bf16 x Bt[N][1024] bf16 ----------------
// EPI 0: N=3072 (Q_eff|K|V stacked). Q,K -> natural [B,S,E] bf16; V -> [b,h,d,s] bf16.
// EPI 1: N=1024, fp32 out + bias.
template <int EPI>
__global__ __launch_bounds__(256) void gemm_bt_kernel(
    const bf16* __restrict__ A, const bf16* __restrict__ Bt,
    const float* __restrict__ bias_q, const float* __restrict__ bias_k,
    const float* __restrict__ bias_v, const float* __restrict__ bias_o,
    bf16* __restrict__ Qp, bf16* __restrict__ Kp, bf16* __restrict__ Vt,
    float* __restrict__ Fout) {
  const int tid = threadIdx.x;
  const int lane = tid & 63, w = tid >> 6;
  const int g = lane >> 4, r15 = lane & 15;
  const int wr = w >> 1, wc = w & 1;
  const int bm = blockIdx.x * 128;
  const int bn = blockIdx.y * 128;

  __shared__ bf16 sA[128 * 32];
  __shared__ bf16 sB[128 * 32];

  f32x4 acc[4][4];
#pragma unroll
  for (int m = 0; m < 4; m++)
#pragma unroll
    for (int n = 0; n < 4; n++) acc[m][n] = (f32x4){0.f, 0.f, 0.f, 0.f};

  const int srow = tid >> 2;
  const int scol = (tid & 3) << 3;
  const bf16* aptr = A + (size_t)(bm + srow) * EMBED + scol;
  const bf16* bptr = Bt + (size_t)(bn + srow) * EMBED + scol;
  bf16* la = sA + tid * 8;
  bf16* lb = sB + tid * 8;

  for (int k0 = 0; k0 < EMBED; k0 += 32) {
    __syncthreads();
    gld_lds16(aptr + k0, la);
    gld_lds16(aptr + k0 + 64 * EMBED, la + 64 * 32);
    gld_lds16(bptr + k0, lb);
    gld_lds16(bptr + k0 + 64 * EMBED, lb + 64 * 32);
    __syncthreads();
    bf16x8 af[4], bfv[4];
#pragma unroll
    for (int m = 0; m < 4; m++)
      af[m] = *(const bf16x8*)&sA[(wr * 64 + m * 16 + r15) * 32 + g * 8];
#pragma unroll
    for (int n = 0; n < 4; n++)
      bfv[n] = *(const bf16x8*)&sB[(wc * 64 + n * 16 + r15) * 32 + g * 8];
#pragma unroll
    for (int m = 0; m < 4; m++)
#pragma unroll
      for (int n = 0; n < 4; n++) acc[m][n] = mfma16(af[m], bfv[n], acc[m][n]);
  }

  const int orow0 = bm + wr * 64;
  if (EPI == 0) {
    const int seg = bn >> 10;
    const int clb = (bn & 1023) + wc * 64;
#pragma unroll
    for (int n = 0; n < 4; n++) {
      const int cl = clb + n * 16 + r15;
      const float bias = (seg == 0) ? bias_q[cl] : (seg == 1) ? bias_k[cl] : bias_v[cl];
#pragma unroll
      for (int m = 0; m < 4; m++) {
        const int row0 = orow0 + m * 16 + g * 4;
        if (seg == 2) {
          const int b = row0 >> 11, s = row0 & 2047;
          const int hh = cl >> 6, d = cl & 63;
          bf16x4 pk;
#pragma unroll
          for (int r = 0; r < 4; r++) pk[r] = (bf16)(acc[m][n][r] + bias);
          *(bf16x4*)(Vt + ((size_t)((b * NH + hh) * HD + d)) * SEQ + s) = pk;
        } else {
          bf16* dst = ((seg == 0) ? Qp : Kp) + (size_t)row0 * EMBED + cl;
#pragma unroll
          for (int r = 0; r < 4; r++) dst[(size_t)r * EMBED] = (bf16)(acc[m][n][r] + bias);
        }
      }
    }
  } else {
    const int ocol0 = bn + wc * 64;
#pragma unroll
    for (int n = 0; n < 4; n++) {
      const int col = ocol0 + n * 16 + r15;
      const float bias = bias_o[col];
#pragma unroll
      for (int m = 0; m < 4; m++) {
        const int row0 = orow0 + m * 16 + g * 4;
#pragma unroll
        for (int r = 0; r < 4; r++)
          Fout[(size_t)(row0 + r) * EMBED + col] = acc[m][n][r] + bias;
      }
    }
  }
}

// ---------------- flash attention ----------------
// grid (32 q-tiles, 32 b*h), 256 thr. Per wave: 16 q rows. KV block = 64.
// scores = Q' K^T (scale already folded into Q' via E').
__global__ __launch_bounds__(256) void flash_attn_kernel(
    const bf16* __restrict__ Qp, const bf16* __restrict__ Kp,
    const bf16* __restrict__ Vt, bf16* __restrict__ Op) {
  const int tid = threadIdx.x, lane = tid & 63, w = tid >> 6;
  const int g = lane >> 4, r15 = lane & 15;
  const int qt = blockIdx.x;
  const int bh = blockIdx.y;
  const int b = bh >> 4, h = bh & 15;

  __shared__ bf16 Plds[4][16 * 64];
  char* pbase = (char*)&Plds[w][0];

  const int qrow = qt * 64 + w * 16 + r15;
  const bf16* qptr = Qp + ((size_t)(b * SEQ + qrow)) * EMBED + h * HD;
  bf16x8 aq0 = *(const bf16x8*)(qptr + g * 8);
  bf16x8 aq1 = *(const bf16x8*)(qptr + 32 + g * 8);

  f32x4 accv[4];
#pragma unroll
  for (int dt = 0; dt < 4; dt++) accv[dt] = (f32x4){0.f, 0.f, 0.f, 0.f};
  float mrow[4], lrow[4];
#pragma unroll
  for (int r = 0; r < 4; r++) { mrow[r] = -3.0e38f; lrow[r] = 0.f; }

  const bf16* kbase = Kp + (size_t)b * SEQ * EMBED + h * HD;
  const bf16* vbase = Vt + (size_t)bh * HD * SEQ;

  for (int kv0 = 0; kv0 < SEQ; kv0 += 64) {
    f32x4 sv[4];
#pragma unroll
    for (int t = 0; t < 4; t++) {
      const bf16* kp = kbase + (size_t)(kv0 + t * 16 + r15) * EMBED;
      bf16x8 bk0 = *(const bf16x8*)(kp + g * 8);
      bf16x8 bk1 = *(const bf16x8*)(kp + 32 + g * 8);
      f32x4 z = (f32x4){0.f, 0.f, 0.f, 0.f};
      z = mfma16(aq0, bk0, z);
      z = mfma16(aq1, bk1, z);
      sv[t] = z;
    }
    float mt[4];
#pragma unroll
    for (int r = 0; r < 4; r++)
      mt[r] = fmaxf(fmaxf(sv[0][r], sv[1][r]), fmaxf(sv[2][r], sv[3][r]));
#pragma unroll
    for (int msk = 1; msk < 16; msk <<= 1)
#pragma unroll
      for (int r = 0; r < 4; r++) mt[r] = fmaxf(mt[r], __shfl_xor(mt[r], msk));
    float alpha[4];
#pragma unroll
    for (int r = 0; r < 4; r++) {
      float mn = fmaxf(mrow[r], mt[r]);
      alpha[r] = __expf(mrow[r] - mn);
      mrow[r] = mn;
    }
    float ps[4] = {0.f, 0.f, 0.f, 0.f};
#pragma unroll
    for (int t = 0; t < 4; t++)
#pragma unroll
      for (int r = 0; r < 4; r++) {
        float p = __expf(sv[t][r] - mrow[r]);
        ps[r] += p;
        int row = g * 4 + r;
        int off = (row * 128 + (t * 16 + r15) * 2) ^ ((row & 7) << 4);
        *(bf16*)(pbase + off) = (bf16)p;
      }
#pragma unroll
    for (int msk = 1; msk < 16; msk <<= 1)
#pragma unroll
      for (int r = 0; r < 4; r++) ps[r] += __shfl_xor(ps[r], msk);
    f32x4 al;
#pragma unroll
    for (int r = 0; r < 4; r++) {
      lrow[r] = lrow[r] * alpha[r] + ps[r];
      al[r] = alpha[r];
    }
#pragma unroll
    for (int dt = 0; dt < 4; dt++) accv[dt] *= al;

    const int rowp = r15;
    int offp0 = (rowp * 128 + (g * 8) * 2) ^ ((rowp & 7) << 4);
    int offp1 = (rowp * 128 + (32 + g * 8) * 2) ^ ((rowp & 7) << 4);
    bf16x8 pa0 = *(const bf16x8*)(pbase + offp0);
    bf16x8 pa1 = *(const bf16x8*)(pbase + offp1);
#pragma unroll
    for (int dt = 0; dt < 4; dt++) {
      const bf16* vp = vbase + (size_t)(dt * 16 + r15) * SEQ + kv0;
      bf16x8 bv0 = *(const bf16x8*)(vp + g * 8);
      bf16x8 bv1 = *(const bf16x8*)(vp + 32 + g * 8);
      accv[dt] = mfma16(pa0, bv0, accv[dt]);
      accv[dt] = mfma16(pa1, bv1, accv[dt]);
    }
  }
#pragma unroll
  for (int dt = 0; dt < 4; dt++)
#pragma unroll
    for (int r = 0; r < 4; r++) {
      int row = qt * 64 + w * 16 + g * 4 + r;
      int col = h * HD + dt * 16 + r15;
      Op[((size_t)(b * SEQ + row)) * EMBED + col] = (bf16)(accv[dt][r] / lrow[r]);
    }
}

// ---------------- launch ----------------
extern "C" void kernel_launch(void* const* d_in, const int* in_sizes, int n_in,
                              void* d_out, int out_size, void* d_ws, size_t ws_size,
                              hipStream_t stream) {
  const float* x     = (const float*)d_in[0];
  const float* q_w   = (const float*)d_in[1];
  const float* q_b   = (const float*)d_in[2];
  const float* k_w   = (const float*)d_in[3];
  const float* k_b   = (const float*)d_in[4];
  const float* v_w   = (const float*)d_in[5];
  const float* v_b   = (const float*)d_in[6];
  const float* phase = (const float*)d_in[7];
  const float* ent   = (const float*)d_in[8];
  const float* out_w = (const float*)d_in[9];
  const float* out_b = (const float*)d_in[10];
  float* out = (float*)d_out;

  char* ws = (char*)d_ws;
  bf16* xb    = (bf16*)(ws + 0);          // 8388608 B, [B,S,E] bf16; reused as attn out
  bf16* wtall = (bf16*)(ws + 8388608);    // 6291456 B, [3072][1024] bf16 (Qeff|K|V)
  bf16* wot   = (bf16*)(ws + 14680064);   // 2097152 B, out_w^T bf16
  float* beff = (float*)(ws + 16777216);  // 4096 B
  bf16* Qp    = (bf16*)(ws + 16781312);   // 8388608 B
  bf16* Kp    = (bf16*)(ws + 25169920);   // 8388608 B
  bf16* Vt    = (bf16*)(ws + 33558528);   // 8388608 B, [b,h,d,s]
  (void)in_sizes; (void)n_in; (void)out_size; (void)ws_size;

  cvt_x_kernel<<<2048, 256, 0, stream>>>(x, xb, MTOK * EMBED / 4);
  transpose_wt_kernel<<<dim3(16, 16), 256, 0, stream>>>(k_w, wtall + 1024 * 1024);
  transpose_wt_kernel<<<dim3(16, 16), 256, 0, stream>>>(v_w, wtall + 2 * 1024 * 1024);
  transpose_wt_kernel<<<dim3(16, 16), 256, 0, stream>>>(out_w, wot);
  weff_kernel<<<dim3(16, 16), 256, 0, stream>>>(q_w, ent, phase, wtall);
  beff_kernel<<<16, 64, 0, stream>>>(q_b, ent, phase, beff);

  gemm_bt_kernel<0><<<dim3(32, 24), 256, 0, stream>>>(
      xb, wtall, beff, k_b, v_b, nullptr, Qp, Kp, Vt, nullptr);

  flash_attn_kernel<<<dim3(32, 32), 256, 0, stream>>>(Qp, Kp, Vt, xb);

  gemm_bt_kernel<1><<<dim3(32, 8), 256, 0, stream>>>(
      xb, wot, nullptr, nullptr, nullptr, out_b, nullptr, nullptr, nullptr, out);
}

// Round 2
// 217.212 us; speedup vs baseline: 1.5164x; 1.5164x over previous
//
#include <hip/hip_runtime.h>
#include <hip/hip_bf16.h>

typedef __bf16 bf16;
typedef __bf16 bf16x8 __attribute__((ext_vector_type(8)));
typedef __bf16 bf16x4 __attribute__((ext_vector_type(4)));
typedef float f32x4 __attribute__((ext_vector_type(4)));

#define EMBED 1024
#define NH 16
#define HD 64
#define BATCH 2
#define SEQ 2048
#define MTOK 4096

static __device__ __forceinline__ f32x4 mfma16(bf16x8 a, bf16x8 b, f32x4 c) {
  return __builtin_amdgcn_mfma_f32_16x16x32_bf16(a, b, c, 0, 0, 0);
}

static __device__ __forceinline__ void gld_lds16(const bf16* g, bf16* l) {
  __builtin_amdgcn_global_load_lds(
      (const __attribute__((address_space(1))) void*)g,
      (__attribute__((address_space(3))) void*)l, 16, 0, 0);
}

// ---------------- prep: x -> bf16 ----------------
__global__ __launch_bounds__(256) void cvt_x_kernel(const float* __restrict__ x,
                                                    bf16* __restrict__ xb, int n4) {
  int i = blockIdx.x * 256 + threadIdx.x;
  int stride = gridDim.x * 256;
  for (; i < n4; i += stride) {
    f32x4 v = ((const f32x4*)x)[i];
    bf16x4 o;
    o[0] = (bf16)v[0]; o[1] = (bf16)v[1]; o[2] = (bf16)v[2]; o[3] = (bf16)v[3];
    ((bf16x4*)xb)[i] = o;
  }
}

// ---------------- prep: W [K][N] fp32 -> Wt [N][K] bf16 ----------------
__global__ __launch_bounds__(256) void transpose_wt_kernel(const float* __restrict__ W,
                                                           bf16* __restrict__ Wt) {
  __shared__ float tile[64][65];
  const int bc = blockIdx.x * 64;  // n base
  const int br = blockIdx.y * 64;  // k base
  const int tid = threadIdx.x;
#pragma unroll
  for (int j = 0; j < 16; j++) {
    int idx = j * 256 + tid;
    int r = idx >> 6, c = idx & 63;
    tile[r][c] = W[(size_t)(br + r) * EMBED + bc + c];
  }
  __syncthreads();
#pragma unroll
  for (int j = 0; j < 16; j++) {
    int idx = j * 256 + tid;
    int r = idx >> 6, c = idx & 63;
    Wt[(size_t)(bc + r) * EMBED + br + c] = (bf16)tile[c][r];
  }
}

// ---------------- prep: W_q_eff^T = (q_w @ blockdiag(E'))^T, bf16 ----------------
// E'[h][d][e] = ent[h][d][e] + (d==e) * cos(phase[h][d])^2 / 8
__global__ __launch_bounds__(256) void weff_kernel(const float* __restrict__ qw,
                                                   const float* __restrict__ ent,
                                                   const float* __restrict__ phase,
                                                   bf16* __restrict__ WtQ) {
  __shared__ float qt[64][65];
  __shared__ float et[64][65];
  const int h = blockIdx.x;
  const int ibase = blockIdx.y * 64;
  const int tid = threadIdx.x;
#pragma unroll
  for (int j = 0; j < 16; j++) {
    int idx = j * 256 + tid;
    int i = idx >> 6, d = idx & 63;
    qt[i][d] = qw[(size_t)(ibase + i) * EMBED + h * HD + d];
  }
#pragma unroll
  for (int j = 0; j < 16; j++) {
    int idx = j * 256 + tid;
    int d = idx >> 6, e = idx & 63;
    float v = ent[((size_t)h * HD + d) * HD + e];
    if (d == e) { float cp = cosf(phase[h * HD + d]); v += cp * cp * 0.125f; }
    et[d][e] = v;
  }
  __syncthreads();
  const int i = tid & 63;
  const int e0 = (tid >> 6) * 16;
  float s[16];
#pragma unroll
  for (int ee = 0; ee < 16; ee++) s[ee] = 0.f;
  for (int d = 0; d < 64; d++) {
    float qv = qt[i][d];
#pragma unroll
    for (int ee = 0; ee < 16; ee++) s[ee] += qv * et[d][e0 + ee];
  }
#pragma unroll
  for (int ee = 0; ee < 16; ee++)
    WtQ[(size_t)(h * HD + e0 + ee) * EMBED + ibase + i] = (bf16)s[ee];
}

__global__ void beff_kernel(const float* __restrict__ qb, const float* __restrict__ ent,
                            const float* __restrict__ phase, float* __restrict__ beff) {
  const int h = blockIdx.x;
  const int e = threadIdx.x;  // 64
  float s = 0.f;
  for (int d = 0; d < 64; d++) {
    float v = ent[((size_t)h * HD + d) * HD + e];
    if (d == e) { float cp = cosf(phase[h * HD + d]); v += cp * cp * 0.125f; }
    s += qb[h * HD + d] * v;
  }
  beff[h * HD + e] = s;
}

// ---------------- GEMM: A[M][1024] bf16 x Bt[N][1024] bf16 ----------------
template <int EPI>
__global__ __launch_bounds__(256) void gemm_bt_kernel(
    const bf16* __restrict__ A, const bf16* __restrict__ Bt,
    const float* __restrict__ bias_q, const float* __restrict__ bias_k,
    const float* __restrict__ bias_v, const float* __restrict__ bias_o,
    bf16* __restrict__ Qp, bf16* __restrict__ Kp, bf16* __restrict__ Vt,
    float* __restrict__ Fout) {
  const int tid = threadIdx.x;
  const int lane = tid & 63, w = tid >> 6;
  const int g = lane >> 4, r15 = lane & 15;
  const int wr = w >> 1, wc = w & 1;
  const int bm = blockIdx.x * 128;
  const int bn = blockIdx.y * 128;

  __shared__ bf16 sA[128 * 32];
  __shared__ bf16 sB[128 * 32];

  f32x4 acc[4][4];
#pragma unroll
  for (int m = 0; m < 4; m++)
#pragma unroll
    for (int n = 0; n < 4; n++) acc[m][n] = (f32x4){0.f, 0.f, 0.f, 0.f};

  const int srow = tid >> 2;
  const int scol = (tid & 3) << 3;
  const bf16* aptr = A + (size_t)(bm + srow) * EMBED + scol;
  const bf16* bptr = Bt + (size_t)(bn + srow) * EMBED + scol;
  bf16* la = sA + tid * 8;
  bf16* lb = sB + tid * 8;

  for (int k0 = 0; k0 < EMBED; k0 += 32) {
    __syncthreads();
    gld_lds16(aptr + k0, la);
    gld_lds16(aptr + k0 + 64 * EMBED, la + 64 * 32);
    gld_lds16(bptr + k0, lb);
    gld_lds16(bptr + k0 + 64 * EMBED, lb + 64 * 32);
    __syncthreads();
    bf16x8 af[4], bfv[4];
#pragma unroll
    for (int m = 0; m < 4; m++)
      af[m] = *(const bf16x8*)&sA[(wr * 64 + m * 16 + r15) * 32 + g * 8];
#pragma unroll
    for (int n = 0; n < 4; n++)
      bfv[n] = *(const bf16x8*)&sB[(wc * 64 + n * 16 + r15) * 32 + g * 8];
#pragma unroll
    for (int m = 0; m < 4; m++)
#pragma unroll
      for (int n = 0; n < 4; n++) acc[m][n] = mfma16(af[m], bfv[n], acc[m][n]);
  }

  const int orow0 = bm + wr * 64;
  if (EPI == 0) {
    const int seg = bn >> 10;
    const int clb = (bn & 1023) + wc * 64;
#pragma unroll
    for (int n = 0; n < 4; n++) {
      const int cl = clb + n * 16 + r15;
      const float bias = (seg == 0) ? bias_q[cl] : (seg == 1) ? bias_k[cl] : bias_v[cl];
#pragma unroll
      for (int m = 0; m < 4; m++) {
        const int row0 = orow0 + m * 16 + g * 4;
        if (seg == 2) {
          const int b = row0 >> 11, s = row0 & 2047;
          const int hh = cl >> 6, d = cl & 63;
          bf16x4 pk;
#pragma unroll
          for (int r = 0; r < 4; r++) pk[r] = (bf16)(acc[m][n][r] + bias);
          *(bf16x4*)(Vt + ((size_t)((b * NH + hh) * HD + d)) * SEQ + s) = pk;
        } else {
          bf16* dst = ((seg == 0) ? Qp : Kp) + (size_t)row0 * EMBED + cl;
#pragma unroll
          for (int r = 0; r < 4; r++) dst[(size_t)r * EMBED] = (bf16)(acc[m][n][r] + bias);
        }
      }
    }
  } else {
    const int ocol0 = bn + wc * 64;
#pragma unroll
    for (int n = 0; n < 4; n++) {
      const int col = ocol0 + n * 16 + r15;
      const float bias = bias_o[col];
#pragma unroll
      for (int m = 0; m < 4; m++) {
        const int row0 = orow0 + m * 16 + g * 4;
#pragma unroll
        for (int r = 0; r < 4; r++)
          Fout[(size_t)(row0 + r) * EMBED + col] = acc[m][n][r] + bias;
      }
    }
  }
}

// ---------------- flash attention ----------------
// 512 blocks (XCD-swizzled), 256 thr = 4 waves. Per wave: 32 q rows (2 m-tiles).
// K/V tiles 64x64 bf16 double-buffered in LDS (XOR-swizzled via pre-swizzled
// global_load_lds source). Counted vmcnt(4) keeps next tile's loads in flight.
__global__ __launch_bounds__(256) void flash_attn_kernel(
    const bf16* __restrict__ Qp, const bf16* __restrict__ Kp,
    const bf16* __restrict__ Vt, bf16* __restrict__ Op) {
  const int tid = threadIdx.x, lane = tid & 63, w = tid >> 6;
  const int g = lane >> 4, r15 = lane & 15;
  // bijective XCD swizzle: 512 blocks = 8 xcd * 64; chunk = 4 bh * 16 qt
  const int flat = blockIdx.x;
  const int c = (flat & 7) * 64 + (flat >> 3);
  const int bh = c >> 4, qt = c & 15;
  const int b = bh >> 4, h = bh & 15;

  __shared__ bf16 sK[2][4096];  // [buf][64 kv][64 d], swizzled
  __shared__ bf16 sV[2][4096];  // [buf][64 d][64 s], swizzled
  __shared__ bf16 sP[4][2048];  // per-wave [32 q][64 kv], swizzled

  const int strow = tid >> 3;         // 0..31 staging row
  const int stcolb = (tid & 7) << 4;  // staging col byte 0..112

  const char* kgbase = (const char*)(Kp + ((size_t)b * SEQ) * EMBED + h * HD);
  const char* vgbase = (const char*)(Vt + (size_t)bh * HD * SEQ);

  auto stage = [&](int buf, int kv0) {
#pragma unroll
    for (int i = 0; i < 2; i++) {
      const int row = i * 32 + strow;
      const int sb = stcolb ^ ((row & 7) << 4);
      gld_lds16((const bf16*)(kgbase + (size_t)(kv0 + row) * (EMBED * 2) + sb),
                &sK[buf][i * 2048 + tid * 8]);
    }
#pragma unroll
    for (int i = 0; i < 2; i++) {
      const int row = i * 32 + strow;
      const int sb = stcolb ^ ((row & 7) << 4);
      gld_lds16((const bf16*)(vgbase + (size_t)row * (SEQ * 2) + (size_t)kv0 * 2 + sb),
                &sV[buf][i * 2048 + tid * 8]);
    }
  };

  stage(0, 0);

  // Q fragments: per m-tile, lane r15 holds q-row m*16+r15, k-slice g*8
  const int qbase = qt * 128 + w * 32;
  bf16x8 aq[2][2];
#pragma unroll
  for (int m = 0; m < 2; m++) {
    const bf16* qptr = Qp + ((size_t)(b * SEQ + qbase + m * 16 + r15)) * EMBED + h * HD;
    aq[m][0] = *(const bf16x8*)(qptr + g * 8);
    aq[m][1] = *(const bf16x8*)(qptr + 32 + g * 8);
  }

  f32x4 accv[2][4];
#pragma unroll
  for (int m = 0; m < 2; m++)
#pragma unroll
    for (int dt = 0; dt < 4; dt++) accv[m][dt] = (f32x4){0.f, 0.f, 0.f, 0.f};
  float mrow[2][4], lrow[2][4];
#pragma unroll
  for (int m = 0; m < 2; m++)
#pragma unroll
    for (int r = 0; r < 4; r++) { mrow[m][r] = -3.0e38f; lrow[m][r] = 0.f; }

  char* pbase = (char*)&sP[w][0];

  for (int it = 0; it < SEQ / 64; ++it) {
    const int cur = it & 1;
    if (it + 1 < SEQ / 64) {
      stage(cur ^ 1, (it + 1) * 64);
      asm volatile("s_waitcnt vmcnt(4)" ::: "memory");
    } else {
      asm volatile("s_waitcnt vmcnt(0)" ::: "memory");
    }
    __builtin_amdgcn_s_barrier();

    // ---- QK^T ----
    bf16x8 bk[4][2];
#pragma unroll
    for (int t = 0; t < 4; t++) {
      const int row = t * 16 + r15;
#pragma unroll
      for (int sl = 0; sl < 2; sl++) {
        const int off = (row * 128 + sl * 64 + g * 16) ^ ((row & 7) << 4);
        bk[t][sl] = *(const bf16x8*)((const char*)&sK[cur][0] + off);
      }
    }
    f32x4 sv[2][4];
#pragma unroll
    for (int m = 0; m < 2; m++)
#pragma unroll
      for (int t = 0; t < 4; t++) {
        f32x4 z = (f32x4){0.f, 0.f, 0.f, 0.f};
        z = mfma16(aq[m][0], bk[t][0], z);
        z = mfma16(aq[m][1], bk[t][1], z);
        sv[m][t] = z;
      }

    // ---- online softmax (per m-tile) ----
#pragma unroll
    for (int m = 0; m < 2; m++) {
      float mt[4];
#pragma unroll
      for (int r = 0; r < 4; r++)
        mt[r] = fmaxf(fmaxf(sv[m][0][r], sv[m][1][r]), fmaxf(sv[m][2][r], sv[m][3][r]));
#pragma unroll
      for (int msk = 1; msk < 16; msk <<= 1)
#pragma unroll
        for (int r = 0; r < 4; r++) mt[r] = fmaxf(mt[r], __shfl_xor(mt[r], msk));
      float alpha[4];
#pragma unroll
      for (int r = 0; r < 4; r++) {
        const float mn = fmaxf(mrow[m][r], mt[r]);
        alpha[r] = __expf(mrow[m][r] - mn);
        mrow[m][r] = mn;
      }
      float ps[4] = {0.f, 0.f, 0.f, 0.f};
#pragma unroll
      for (int t = 0; t < 4; t++)
#pragma unroll
        for (int r = 0; r < 4; r++) {
          const float p = __expf(sv[m][t][r] - mrow[m][r]);
          ps[r] += p;
          const int row = m * 16 + g * 4 + r;
          const int off = (row * 128 + (t * 16 + r15) * 2) ^ ((row & 7) << 4);
          *(bf16*)(pbase + off) = (bf16)p;
        }
#pragma unroll
      for (int msk = 1; msk < 16; msk <<= 1)
#pragma unroll
        for (int r = 0; r < 4; r++) ps[r] += __shfl_xor(ps[r], msk);
      f32x4 al;
#pragma unroll
      for (int r = 0; r < 4; r++) {
        lrow[m][r] = lrow[m][r] * alpha[r] + ps[r];
        al[r] = alpha[r];
      }
#pragma unroll
      for (int dt = 0; dt < 4; dt++) accv[m][dt] *= al;
    }

    // ---- PV ----
    bf16x8 bv[4][2];
#pragma unroll
    for (int dt = 0; dt < 4; dt++) {
      const int row = dt * 16 + r15;
#pragma unroll
      for (int sl = 0; sl < 2; sl++) {
        const int off = (row * 128 + sl * 64 + g * 16) ^ ((row & 7) << 4);
        bv[dt][sl] = *(const bf16x8*)((const char*)&sV[cur][0] + off);
      }
    }
    bf16x8 pa[2][2];
#pragma unroll
    for (int m = 0; m < 2; m++)
#pragma unroll
      for (int sl = 0; sl < 2; sl++) {
        const int off = ((m * 16 + r15) * 128 + sl * 64 + g * 16) ^ ((r15 & 7) << 4);
        pa[m][sl] = *(const bf16x8*)(pbase + off);
      }
#pragma unroll
    for (int m = 0; m < 2; m++)
#pragma unroll
      for (int dt = 0; dt < 4; dt++) {
        accv[m][dt] = mfma16(pa[m][0], bv[dt][0], accv[m][dt]);
        accv[m][dt] = mfma16(pa[m][1], bv[dt][1], accv[m][dt]);
      }
    __builtin_amdgcn_s_barrier();
  }

#pragma unroll
  for (int m = 0; m < 2; m++)
#pragma unroll
    for (int dt = 0; dt < 4; dt++)
#pragma unroll
      for (int r = 0; r < 4; r++) {
        const int row = qbase + m * 16 + g * 4 + r;
        const int col = h * HD + dt * 16 + r15;
        Op[((size_t)(b * SEQ + row)) * EMBED + col] = (bf16)(accv[m][dt][r] / lrow[m][r]);
      }
}

// ---------------- launch ----------------
extern "C" void kernel_launch(void* const* d_in, const int* in_sizes, int n_in,
                              void* d_out, int out_size, void* d_ws, size_t ws_size,
                              hipStream_t stream) {
  const float* x     = (const float*)d_in[0];
  const float* q_w   = (const float*)d_in[1];
  const float* q_b   = (const float*)d_in[2];
  const float* k_w   = (const float*)d_in[3];
  const float* k_b   = (const float*)d_in[4];
  const float* v_w   = (const float*)d_in[5];
  const float* v_b   = (const float*)d_in[6];
  const float* phase = (const float*)d_in[7];
  const float* ent   = (const float*)d_in[8];
  const float* out_w = (const float*)d_in[9];
  const float* out_b = (const float*)d_in[10];
  float* out = (float*)d_out;

  char* ws = (char*)d_ws;
  bf16* xb    = (bf16*)(ws + 0);          // 8388608 B, [B,S,E] bf16; reused as attn out
  bf16* wtall = (bf16*)(ws + 8388608);    // 6291456 B, [3072][1024] bf16 (Qeff|K|V)
  bf16* wot   = (bf16*)(ws + 14680064);   // 2097152 B, out_w^T bf16
  float* beff = (float*)(ws + 16777216);  // 4096 B
  bf16* Qp    = (bf16*)(ws + 16781312);   // 8388608 B
  bf16* Kp    = (bf16*)(ws + 25169920);   // 8388608 B
  bf16* Vt    = (bf16*)(ws + 33558528);   // 8388608 B, [b,h,d,s]
  (void)in_sizes; (void)n_in; (void)out_size; (void)ws_size;

  cvt_x_kernel<<<2048, 256, 0, stream>>>(x, xb, MTOK * EMBED / 4);
  transpose_wt_kernel<<<dim3(16, 16), 256, 0, stream>>>(k_w, wtall + 1024 * 1024);
  transpose_wt_kernel<<<dim3(16, 16), 256, 0, stream>>>(v_w, wtall + 2 * 1024 * 1024);
  transpose_wt_kernel<<<dim3(16, 16), 256, 0, stream>>>(out_w, wot);
  weff_kernel<<<dim3(16, 16), 256, 0, stream>>>(q_w, ent, phase, wtall);
  beff_kernel<<<16, 64, 0, stream>>>(q_b, ent, phase, beff);

  gemm_bt_kernel<0><<<dim3(32, 24), 256, 0, stream>>>(
      xb, wtall, beff, k_b, v_b, nullptr, Qp, Kp, Vt, nullptr);

  flash_attn_kernel<<<512, 256, 0, stream>>>(Qp, Kp, Vt, xb);

  gemm_bt_kernel<1><<<dim3(32, 8), 256, 0, stream>>>(
      xb, wot, nullptr, nullptr, nullptr, out_b, nullptr, nullptr, nullptr, out);
}

// Round 4
// 198.263 us; speedup vs baseline: 1.6613x; 1.0956x over previous
//
#include <hip/hip_runtime.h>
#include <hip/hip_bf16.h>

typedef __bf16 bf16;
typedef __bf16 bf16x8 __attribute__((ext_vector_type(8)));
typedef __bf16 bf16x4 __attribute__((ext_vector_type(4)));
typedef float f32x4 __attribute__((ext_vector_type(4)));

#define EMBED 1024
#define NH 16
#define HD 64
#define BATCH 2
#define SEQ 2048
#define MTOK 4096
#define LOG2E 1.4426950408889634f

static __device__ __forceinline__ float fast_exp2(float x) {
#if __has_builtin(__builtin_amdgcn_exp2f)
  return __builtin_amdgcn_exp2f(x);
#else
  float r;
  asm("v_exp_f32 %0, %1" : "=v"(r) : "v"(x));
  return r;
#endif
}

static __device__ __forceinline__ f32x4 mfma16(bf16x8 a, bf16x8 b, f32x4 c) {
  return __builtin_amdgcn_mfma_f32_16x16x32_bf16(a, b, c, 0, 0, 0);
}

static __device__ __forceinline__ void gld_lds16(const bf16* g, bf16* l) {
  __builtin_amdgcn_global_load_lds(
      (const __attribute__((address_space(1))) void*)g,
      (__attribute__((address_space(3))) void*)l, 16, 0, 0);
}

// ---------------- prep: x -> bf16 ----------------
__global__ __launch_bounds__(256) void cvt_x_kernel(const float* __restrict__ x,
                                                    bf16* __restrict__ xb, int n4) {
  int i = blockIdx.x * 256 + threadIdx.x;
  int stride = gridDim.x * 256;
  for (; i < n4; i += stride) {
    f32x4 v = ((const f32x4*)x)[i];
    bf16x4 o;
    o[0] = (bf16)v[0]; o[1] = (bf16)v[1]; o[2] = (bf16)v[2]; o[3] = (bf16)v[3];
    ((bf16x4*)xb)[i] = o;
  }
}

// ---------------- prep: W [K][N] fp32 -> Wt [N][K] bf16 ----------------
__global__ __launch_bounds__(256) void transpose_wt_kernel(const float* __restrict__ W,
                                                           bf16* __restrict__ Wt) {
  __shared__ float tile[64][65];
  const int bc = blockIdx.x * 64;  // n base
  const int br = blockIdx.y * 64;  // k base
  const int tid = threadIdx.x;
#pragma unroll
  for (int j = 0; j < 16; j++) {
    int idx = j * 256 + tid;
    int r = idx >> 6, c = idx & 63;
    tile[r][c] = W[(size_t)(br + r) * EMBED + bc + c];
  }
  __syncthreads();
#pragma unroll
  for (int j = 0; j < 16; j++) {
    int idx = j * 256 + tid;
    int r = idx >> 6, c = idx & 63;
    Wt[(size_t)(bc + r) * EMBED + br + c] = (bf16)tile[c][r];
  }
}

// ---------------- prep: W_q_eff^T = (q_w @ blockdiag(E')*log2e)^T, bf16 ----------------
// E'[h][d][e] = (ent[h][d][e] + (d==e) * cos(phase[h][d])^2 / 8) * LOG2E
__global__ __launch_bounds__(256) void weff_kernel(const float* __restrict__ qw,
                                                   const float* __restrict__ ent,
                                                   const float* __restrict__ phase,
                                                   bf16* __restrict__ WtQ) {
  __shared__ float qt[64][65];
  __shared__ float et[64][65];
  const int h = blockIdx.x;
  const int ibase = blockIdx.y * 64;
  const int tid = threadIdx.x;
#pragma unroll
  for (int j = 0; j < 16; j++) {
    int idx = j * 256 + tid;
    int i = idx >> 6, d = idx & 63;
    qt[i][d] = qw[(size_t)(ibase + i) * EMBED + h * HD + d];
  }
#pragma unroll
  for (int j = 0; j < 16; j++) {
    int idx = j * 256 + tid;
    int d = idx >> 6, e = idx & 63;
    float v = ent[((size_t)h * HD + d) * HD + e];
    if (d == e) { float cp = cosf(phase[h * HD + d]); v += cp * cp * 0.125f; }
    et[d][e] = v * LOG2E;
  }
  __syncthreads();
  const int i = tid & 63;
  const int e0 = (tid >> 6) * 16;
  float s[16];
#pragma unroll
  for (int ee = 0; ee < 16; ee++) s[ee] = 0.f;
  for (int d = 0; d < 64; d++) {
    float qv = qt[i][d];
#pragma unroll
    for (int ee = 0; ee < 16; ee++) s[ee] += qv * et[d][e0 + ee];
  }
#pragma unroll
  for (int ee = 0; ee < 16; ee++)
    WtQ[(size_t)(h * HD + e0 + ee) * EMBED + ibase + i] = (bf16)s[ee];
}

__global__ void beff_kernel(const float* __restrict__ qb, const float* __restrict__ ent,
                            const float* __restrict__ phase, float* __restrict__ beff) {
  const int h = blockIdx.x;
  const int e = threadIdx.x;  // 64
  float s = 0.f;
  for (int d = 0; d < 64; d++) {
    float v = ent[((size_t)h * HD + d) * HD + e];
    if (d == e) { float cp = cosf(phase[h * HD + d]); v += cp * cp * 0.125f; }
    s += qb[h * HD + d] * v;
  }
  beff[h * HD + e] = s * LOG2E;
}

// ---------------- GEMM: A[M][1024] bf16 x Bt[N][1024] bf16 ----------------
template <int EPI>
__global__ __launch_bounds__(256) void gemm_bt_kernel(
    const bf16* __restrict__ A, const bf16* __restrict__ Bt,
    const float* __restrict__ bias_q, const float* __restrict__ bias_k,
    const float* __restrict__ bias_v, const float* __restrict__ bias_o,
    bf16* __restrict__ Qp, bf16* __restrict__ Kp, bf16* __restrict__ Vt,
    float* __restrict__ Fout) {
  const int tid = threadIdx.x;
  const int lane = tid & 63, w = tid >> 6;
  const int g = lane >> 4, r15 = lane & 15;
  const int wr = w >> 1, wc = w & 1;
  const int bm = blockIdx.x * 128;
  const int bn = blockIdx.y * 128;

  __shared__ bf16 sA[128 * 32];
  __shared__ bf16 sB[128 * 32];

  f32x4 acc[4][4];
#pragma unroll
  for (int m = 0; m < 4; m++)
#pragma unroll
    for (int n = 0; n < 4; n++) acc[m][n] = (f32x4){0.f, 0.f, 0.f, 0.f};

  const int srow = tid >> 2;
  const int scol = (tid & 3) << 3;
  const bf16* aptr = A + (size_t)(bm + srow) * EMBED + scol;
  const bf16* bptr = Bt + (size_t)(bn + srow) * EMBED + scol;
  bf16* la = sA + tid * 8;
  bf16* lb = sB + tid * 8;

  for (int k0 = 0; k0 < EMBED; k0 += 32) {
    __syncthreads();
    gld_lds16(aptr + k0, la);
    gld_lds16(aptr + k0 + 64 * EMBED, la + 64 * 32);
    gld_lds16(bptr + k0, lb);
    gld_lds16(bptr + k0 + 64 * EMBED, lb + 64 * 32);
    __syncthreads();
    bf16x8 af[4], bfv[4];
#pragma unroll
    for (int m = 0; m < 4; m++)
      af[m] = *(const bf16x8*)&sA[(wr * 64 + m * 16 + r15) * 32 + g * 8];
#pragma unroll
    for (int n = 0; n < 4; n++)
      bfv[n] = *(const bf16x8*)&sB[(wc * 64 + n * 16 + r15) * 32 + g * 8];
#pragma unroll
    for (int m = 0; m < 4; m++)
#pragma unroll
      for (int n = 0; n < 4; n++) acc[m][n] = mfma16(af[m], bfv[n], acc[m][n]);
  }

  const int orow0 = bm + wr * 64;
  if (EPI == 0) {
    const int seg = bn >> 10;
    const int clb = (bn & 1023) + wc * 64;
#pragma unroll
    for (int n = 0; n < 4; n++) {
      const int cl = clb + n * 16 + r15;
      const float bias = (seg == 0) ? bias_q[cl] : (seg == 1) ? bias_k[cl] : bias_v[cl];
#pragma unroll
      for (int m = 0; m < 4; m++) {
        const int row0 = orow0 + m * 16 + g * 4;
        if (seg == 2) {
          const int b = row0 >> 11, s = row0 & 2047;
          const int hh = cl >> 6, d = cl & 63;
          bf16x4 pk;
#pragma unroll
          for (int r = 0; r < 4; r++) pk[r] = (bf16)(acc[m][n][r] + bias);
          *(bf16x4*)(Vt + ((size_t)((b * NH + hh) * HD + d)) * SEQ + s) = pk;
        } else {
          bf16* dst = ((seg == 0) ? Qp : Kp) + (size_t)row0 * EMBED + cl;
#pragma unroll
          for (int r = 0; r < 4; r++) dst[(size_t)r * EMBED] = (bf16)(acc[m][n][r] + bias);
        }
      }
    }
  } else {
    const int ocol0 = bn + wc * 64;
#pragma unroll
    for (int n = 0; n < 4; n++) {
      const int col = ocol0 + n * 16 + r15;
      const float bias = bias_o[col];
#pragma unroll
      for (int m = 0; m < 4; m++) {
        const int row0 = orow0 + m * 16 + g * 4;
#pragma unroll
        for (int r = 0; r < 4; r++)
          Fout[(size_t)(row0 + r) * EMBED + col] = acc[m][n][r] + bias;
      }
    }
  }
}

// ---------------- flash attention ----------------
// 512 blocks (XCD-swizzled) x 512 thr = 8 waves. Per wave: 16 q rows.
// QBLK=128/block. K/V tiles 64x64 bf16 double-buffered in LDS (XOR-swizzled
// via pre-swizzled global_load_lds source); 8 waves share one stage.
// Counted vmcnt(2) keeps next tile's loads in flight. exp2-domain softmax.
__global__ __launch_bounds__(512, 4) void flash_attn_kernel(
    const bf16* __restrict__ Qp, const bf16* __restrict__ Kp,
    const bf16* __restrict__ Vt, bf16* __restrict__ Op) {
  const int tid = threadIdx.x, lane = tid & 63, w = tid >> 6;
  const int g = lane >> 4, r15 = lane & 15;
  // bijective XCD swizzle: 512 blocks = 8 xcd * 64; chunk = 4 bh * 16 qt
  const int flat = blockIdx.x;
  const int c = (flat & 7) * 64 + (flat >> 3);
  const int bh = c >> 4, qt = c & 15;
  const int b = bh >> 4, h = bh & 15;

  __shared__ bf16 sK[2][4096];  // [buf][64 kv][64 d], swizzled
  __shared__ bf16 sV[2][4096];  // [buf][64 d][64 s], swizzled
  __shared__ bf16 sP[8][1024];  // per-wave [16 q][64 kv], swizzled

  const int strow = tid >> 3;         // 0..63 staging row
  const int stcolb = (tid & 7) << 4;  // staging col byte 0..112
  const int stsb = stcolb ^ ((strow & 7) << 4);

  const char* kgbase = (const char*)(Kp + ((size_t)b * SEQ) * EMBED + h * HD);
  const char* vgbase = (const char*)(Vt + (size_t)bh * HD * SEQ);

  auto stage = [&](int buf, int kv0) {
    gld_lds16((const bf16*)(kgbase + (size_t)(kv0 + strow) * (EMBED * 2) + stsb),
              &sK[buf][tid * 8]);
    gld_lds16((const bf16*)(vgbase + (size_t)strow * (SEQ * 2) + (size_t)kv0 * 2 + stsb),
              &sV[buf][tid * 8]);
  };

  stage(0, 0);

  // Q fragments: lane r15 holds q-row qbase+r15, k-slice g*8
  const int qbase = qt * 128 + w * 16;
  const bf16* qptr = Qp + ((size_t)(b * SEQ + qbase + r15)) * EMBED + h * HD;
  bf16x8 aq0 = *(const bf16x8*)(qptr + g * 8);
  bf16x8 aq1 = *(const bf16x8*)(qptr + 32 + g * 8);

  f32x4 accv[4];
#pragma unroll
  for (int dt = 0; dt < 4; dt++) accv[dt] = (f32x4){0.f, 0.f, 0.f, 0.f};
  float mrow[4], lrow[4];
#pragma unroll
  for (int r = 0; r < 4; r++) { mrow[r] = -3.0e38f; lrow[r] = 0.f; }

  char* pbase = (char*)&sP[w][0];

  for (int it = 0; it < SEQ / 64; ++it) {
    const int cur = it & 1;
    if (it + 1 < SEQ / 64) {
      stage(cur ^ 1, (it + 1) * 64);
      asm volatile("s_waitcnt vmcnt(2)" ::: "memory");
    } else {
      asm volatile("s_waitcnt vmcnt(0)" ::: "memory");
    }
    __builtin_amdgcn_s_barrier();

    // ---- QK^T ----
    bf16x8 bk[4][2];
#pragma unroll
    for (int t = 0; t < 4; t++) {
      const int row = t * 16 + r15;
#pragma unroll
      for (int sl = 0; sl < 2; sl++) {
        const int off = (row * 128 + sl * 64 + g * 16) ^ ((row & 7) << 4);
        bk[t][sl] = *(const bf16x8*)((const char*)&sK[cur][0] + off);
      }
    }
    f32x4 sv[4];
    __builtin_amdgcn_s_setprio(1);
#pragma unroll
    for (int t = 0; t < 4; t++) {
      f32x4 z = (f32x4){0.f, 0.f, 0.f, 0.f};
      z = mfma16(aq0, bk[t][0], z);
      z = mfma16(aq1, bk[t][1], z);
      sv[t] = z;
    }
    __builtin_amdgcn_s_setprio(0);

    // ---- online softmax (exp2 domain; scores pre-scaled by log2e) ----
    float mt[4];
#pragma unroll
    for (int r = 0; r < 4; r++)
      mt[r] = fmaxf(fmaxf(sv[0][r], sv[1][r]), fmaxf(sv[2][r], sv[3][r]));
#pragma unroll
    for (int msk = 1; msk < 16; msk <<= 1)
#pragma unroll
      for (int r = 0; r < 4; r++) mt[r] = fmaxf(mt[r], __shfl_xor(mt[r], msk));
    float alpha[4];
#pragma unroll
    for (int r = 0; r < 4; r++) {
      const float mn = fmaxf(mrow[r], mt[r]);
      alpha[r] = fast_exp2(mrow[r] - mn);
      mrow[r] = mn;
    }
    float ps[4] = {0.f, 0.f, 0.f, 0.f};
#pragma unroll
    for (int t = 0; t < 4; t++)
#pragma unroll
      for (int r = 0; r < 4; r++) {
        const float p = fast_exp2(sv[t][r] - mrow[r]);
        ps[r] += p;
        const int row = g * 4 + r;
        const int off = (row * 128 + (t * 16 + r15) * 2) ^ ((row & 7) << 4);
        *(bf16*)(pbase + off) = (bf16)p;
      }
#pragma unroll
    for (int msk = 1; msk < 16; msk <<= 1)
#pragma unroll
      for (int r = 0; r < 4; r++) ps[r] += __shfl_xor(ps[r], msk);
    f32x4 al;
#pragma unroll
    for (int r = 0; r < 4; r++) {
      lrow[r] = lrow[r] * alpha[r] + ps[r];
      al[r] = alpha[r];
    }
#pragma unroll
    for (int dt = 0; dt < 4; dt++) accv[dt] *= al;

    // ---- PV ----
    bf16x8 bv[4][2];
#pragma unroll
    for (int dt = 0; dt < 4; dt++) {
      const int row = dt * 16 + r15;
#pragma unroll
      for (int sl = 0; sl < 2; sl++) {
        const int off = (row * 128 + sl * 64 + g * 16) ^ ((row & 7) << 4);
        bv[dt][sl] = *(const bf16x8*)((const char*)&sV[cur][0] + off);
      }
    }
    bf16x8 pa[2];
#pragma unroll
    for (int sl = 0; sl < 2; sl++) {
      const int off = (r15 * 128 + sl * 64 + g * 16) ^ ((r15 & 7) << 4);
      pa[sl] = *(const bf16x8*)(pbase + off);
    }
    __builtin_amdgcn_s_setprio(1);
#pragma unroll
    for (int dt = 0; dt < 4; dt++) {
      accv[dt] = mfma16(pa[0], bv[dt][0], accv[dt]);
      accv[dt] = mfma16(pa[1], bv[dt][1], accv[dt]);
    }
    __builtin_amdgcn_s_setprio(0);
    __builtin_amdgcn_s_barrier();
  }

#pragma unroll
  for (int dt = 0; dt < 4; dt++)
#pragma unroll
    for (int r = 0; r < 4; r++) {
      const int row = qbase + g * 4 + r;
      const int col = h * HD + dt * 16 + r15;
      Op[((size_t)(b * SEQ + row)) * EMBED + col] = (bf16)(accv[dt][r] / lrow[r]);
    }
}

// ---------------- launch ----------------
extern "C" void kernel_launch(void* const* d_in, const int* in_sizes, int n_in,
                              void* d_out, int out_size, void* d_ws, size_t ws_size,
                              hipStream_t stream) {
  const float* x     = (const float*)d_in[0];
  const float* q_w   = (const float*)d_in[1];
  const float* q_b   = (const float*)d_in[2];
  const float* k_w   = (const float*)d_in[3];
  const float* k_b   = (const float*)d_in[4];
  const float* v_w   = (const float*)d_in[5];
  const float* v_b   = (const float*)d_in[6];
  const float* phase = (const float*)d_in[7];
  const float* ent   = (const float*)d_in[8];
  const float* out_w = (const float*)d_in[9];
  const float* out_b = (const float*)d_in[10];
  float* out = (float*)d_out;

  char* ws = (char*)d_ws;
  bf16* xb    = (bf16*)(ws + 0);          // 8388608 B, [B,S,E] bf16; reused as attn out
  bf16* wtall = (bf16*)(ws + 8388608);    // 6291456 B, [3072][1024] bf16 (Qeff|K|V)
  bf16* wot   = (bf16*)(ws + 14680064);   // 2097152 B, out_w^T bf16
  float* beff = (float*)(ws + 16777216);  // 4096 B
  bf16* Qp    = (bf16*)(ws + 16781312);   // 8388608 B
  bf16* Kp    = (bf16*)(ws + 25169920);   // 8388608 B
  bf16* Vt    = (bf16*)(ws + 33558528);   // 8388608 B, [b,h,d,s]
  (void)in_sizes; (void)n_in; (void)out_size; (void)ws_size;

  cvt_x_kernel<<<2048, 256, 0, stream>>>(x, xb, MTOK * EMBED / 4);
  transpose_wt_kernel<<<dim3(16, 16), 256, 0, stream>>>(k_w, wtall + 1024 * 1024);
  transpose_wt_kernel<<<dim3(16, 16), 256, 0, stream>>>(v_w, wtall + 2 * 1024 * 1024);
  transpose_wt_kernel<<<dim3(16, 16), 256, 0, stream>>>(out_w, wot);
  weff_kernel<<<dim3(16, 16), 256, 0, stream>>>(q_w, ent, phase, wtall);
  beff_kernel<<<16, 64, 0, stream>>>(q_b, ent, phase, beff);

  gemm_bt_kernel<0><<<dim3(32, 24), 256, 0, stream>>>(
      xb, wtall, beff, k_b, v_b, nullptr, Qp, Kp, Vt, nullptr);

  flash_attn_kernel<<<512, 512, 0, stream>>>(Qp, Kp, Vt, xb);

  gemm_bt_kernel<1><<<dim3(32, 8), 256, 0, stream>>>(
      xb, wot, nullptr, nullptr, nullptr, out_b, nullptr, nullptr, nullptr, out);
}

// Round 5
// 171.057 us; speedup vs baseline: 1.9255x; 1.1590x over previous
//
#include <hip/hip_runtime.h>
#include <hip/hip_bf16.h>

typedef __bf16 bf16;
typedef __bf16 bf16x8 __attribute__((ext_vector_type(8)));
typedef __bf16 bf16x4 __attribute__((ext_vector_type(4)));
typedef float f32x4 __attribute__((ext_vector_type(4)));

#define EMBED 1024
#define NH 16
#define HD 64
#define BATCH 2
#define SEQ 2048
#define MTOK 4096
#define LOG2E 1.4426950408889634f

static __device__ __forceinline__ float fast_exp2(float x) {
#if __has_builtin(__builtin_amdgcn_exp2f)
  return __builtin_amdgcn_exp2f(x);
#else
  float r;
  asm("v_exp_f32 %0, %1" : "=v"(r) : "v"(x));
  return r;
#endif
}

// fmax with a DPP row-rotate of the source: VALU-pipe 16-lane reduction step
// (row_ror:N rotates within each 16-lane row; our reduce group is r15).
template <int CTRL>
static __device__ __forceinline__ float fmax_dpp(float x) {
  int i = __float_as_int(x);
  int r = __builtin_amdgcn_update_dpp(i, i, CTRL, 0xF, 0xF, false);
  return fmaxf(x, __int_as_float(r));
}

static __device__ __forceinline__ f32x4 mfma16(bf16x8 a, bf16x8 b, f32x4 c) {
  return __builtin_amdgcn_mfma_f32_16x16x32_bf16(a, b, c, 0, 0, 0);
}

static __device__ __forceinline__ void gld_lds16(const bf16* g, bf16* l) {
  __builtin_amdgcn_global_load_lds(
      (const __attribute__((address_space(1))) void*)g,
      (__attribute__((address_space(3))) void*)l, 16, 0, 0);
}

// ---------------- prep: x -> bf16 ----------------
__global__ __launch_bounds__(256) void cvt_x_kernel(const float* __restrict__ x,
                                                    bf16* __restrict__ xb, int n4) {
  int i = blockIdx.x * 256 + threadIdx.x;
  int stride = gridDim.x * 256;
  for (; i < n4; i += stride) {
    f32x4 v = ((const f32x4*)x)[i];
    bf16x4 o;
    o[0] = (bf16)v[0]; o[1] = (bf16)v[1]; o[2] = (bf16)v[2]; o[3] = (bf16)v[3];
    ((bf16x4*)xb)[i] = o;
  }
}

// ---------------- prep: W [K][N] fp32 -> Wt [N][K] bf16 ----------------
__global__ __launch_bounds__(256) void transpose_wt_kernel(const float* __restrict__ W,
                                                           bf16* __restrict__ Wt) {
  __shared__ float tile[64][65];
  const int bc = blockIdx.x * 64;  // n base
  const int br = blockIdx.y * 64;  // k base
  const int tid = threadIdx.x;
#pragma unroll
  for (int j = 0; j < 16; j++) {
    int idx = j * 256 + tid;
    int r = idx >> 6, c = idx & 63;
    tile[r][c] = W[(size_t)(br + r) * EMBED + bc + c];
  }
  __syncthreads();
#pragma unroll
  for (int j = 0; j < 16; j++) {
    int idx = j * 256 + tid;
    int r = idx >> 6, c = idx & 63;
    Wt[(size_t)(bc + r) * EMBED + br + c] = (bf16)tile[c][r];
  }
}

// ---------------- prep: W_q_eff^T = (q_w @ blockdiag(E')*log2e)^T, bf16 ----------------
// E'[h][d][e] = (ent[h][d][e] + (d==e) * cos(phase[h][d])^2 / 8) * LOG2E
__global__ __launch_bounds__(256) void weff_kernel(const float* __restrict__ qw,
                                                   const float* __restrict__ ent,
                                                   const float* __restrict__ phase,
                                                   bf16* __restrict__ WtQ) {
  __shared__ float qt[64][65];
  __shared__ float et[64][65];
  const int h = blockIdx.x;
  const int ibase = blockIdx.y * 64;
  const int tid = threadIdx.x;
#pragma unroll
  for (int j = 0; j < 16; j++) {
    int idx = j * 256 + tid;
    int i = idx >> 6, d = idx & 63;
    qt[i][d] = qw[(size_t)(ibase + i) * EMBED + h * HD + d];
  }
#pragma unroll
  for (int j = 0; j < 16; j++) {
    int idx = j * 256 + tid;
    int d = idx >> 6, e = idx & 63;
    float v = ent[((size_t)h * HD + d) * HD + e];
    if (d == e) { float cp = cosf(phase[h * HD + d]); v += cp * cp * 0.125f; }
    et[d][e] = v * LOG2E;
  }
  __syncthreads();
  const int i = tid & 63;
  const int e0 = (tid >> 6) * 16;
  float s[16];
#pragma unroll
  for (int ee = 0; ee < 16; ee++) s[ee] = 0.f;
  for (int d = 0; d < 64; d++) {
    float qv = qt[i][d];
#pragma unroll
    for (int ee = 0; ee < 16; ee++) s[ee] += qv * et[d][e0 + ee];
  }
#pragma unroll
  for (int ee = 0; ee < 16; ee++)
    WtQ[(size_t)(h * HD + e0 + ee) * EMBED + ibase + i] = (bf16)s[ee];
}

__global__ void beff_kernel(const float* __restrict__ qb, const float* __restrict__ ent,
                            const float* __restrict__ phase, float* __restrict__ beff) {
  const int h = blockIdx.x;
  const int e = threadIdx.x;  // 64
  float s = 0.f;
  for (int d = 0; d < 64; d++) {
    float v = ent[((size_t)h * HD + d) * HD + e];
    if (d == e) { float cp = cosf(phase[h * HD + d]); v += cp * cp * 0.125f; }
    s += qb[h * HD + d] * v;
  }
  beff[h * HD + e] = s * LOG2E;
}

// ---------------- GEMM: A[M][1024] bf16 x Bt[N][1024] bf16 ----------------
template <int EPI>
__global__ __launch_bounds__(256) void gemm_bt_kernel(
    const bf16* __restrict__ A, const bf16* __restrict__ Bt,
    const float* __restrict__ bias_q, const float* __restrict__ bias_k,
    const float* __restrict__ bias_v, const float* __restrict__ bias_o,
    bf16* __restrict__ Qp, bf16* __restrict__ Kp, bf16* __restrict__ Vt,
    float* __restrict__ Fout) {
  const int tid = threadIdx.x;
  const int lane = tid & 63, w = tid >> 6;
  const int g = lane >> 4, r15 = lane & 15;
  const int wr = w >> 1, wc = w & 1;
  const int bm = blockIdx.x * 128;
  const int bn = blockIdx.y * 128;

  __shared__ bf16 sA[128 * 32];
  __shared__ bf16 sB[128 * 32];

  f32x4 acc[4][4];
#pragma unroll
  for (int m = 0; m < 4; m++)
#pragma unroll
    for (int n = 0; n < 4; n++) acc[m][n] = (f32x4){0.f, 0.f, 0.f, 0.f};

  const int srow = tid >> 2;
  const int scol = (tid & 3) << 3;
  const bf16* aptr = A + (size_t)(bm + srow) * EMBED + scol;
  const bf16* bptr = Bt + (size_t)(bn + srow) * EMBED + scol;
  bf16* la = sA + tid * 8;
  bf16* lb = sB + tid * 8;

  for (int k0 = 0; k0 < EMBED; k0 += 32) {
    __syncthreads();
    gld_lds16(aptr + k0, la);
    gld_lds16(aptr + k0 + 64 * EMBED, la + 64 * 32);
    gld_lds16(bptr + k0, lb);
    gld_lds16(bptr + k0 + 64 * EMBED, lb + 64 * 32);
    __syncthreads();
    bf16x8 af[4], bfv[4];
#pragma unroll
    for (int m = 0; m < 4; m++)
      af[m] = *(const bf16x8*)&sA[(wr * 64 + m * 16 + r15) * 32 + g * 8];
#pragma unroll
    for (int n = 0; n < 4; n++)
      bfv[n] = *(const bf16x8*)&sB[(wc * 64 + n * 16 + r15) * 32 + g * 8];
#pragma unroll
    for (int m = 0; m < 4; m++)
#pragma unroll
      for (int n = 0; n < 4; n++) acc[m][n] = mfma16(af[m], bfv[n], acc[m][n]);
  }

  const int orow0 = bm + wr * 64;
  if (EPI == 0) {
    const int seg = bn >> 10;
    const int clb = (bn & 1023) + wc * 64;
#pragma unroll
    for (int n = 0; n < 4; n++) {
      const int cl = clb + n * 16 + r15;
      const float bias = (seg == 0) ? bias_q[cl] : (seg == 1) ? bias_k[cl] : bias_v[cl];
#pragma unroll
      for (int m = 0; m < 4; m++) {
        const int row0 = orow0 + m * 16 + g * 4;
        if (seg == 2) {
          const int b = row0 >> 11, s = row0 & 2047;
          const int hh = cl >> 6, d = cl & 63;
          bf16x4 pk;
#pragma unroll
          for (int r = 0; r < 4; r++) pk[r] = (bf16)(acc[m][n][r] + bias);
          *(bf16x4*)(Vt + ((size_t)((b * NH + hh) * HD + d)) * SEQ + s) = pk;
        } else {
          bf16* dst = ((seg == 0) ? Qp : Kp) + (size_t)row0 * EMBED + cl;
#pragma unroll
          for (int r = 0; r < 4; r++) dst[(size_t)r * EMBED] = (bf16)(acc[m][n][r] + bias);
        }
      }
    }
  } else {
    const int ocol0 = bn + wc * 64;
#pragma unroll
    for (int n = 0; n < 4; n++) {
      const int col = ocol0 + n * 16 + r15;
      const float bias = bias_o[col];
#pragma unroll
      for (int m = 0; m < 4; m++) {
        const int row0 = orow0 + m * 16 + g * 4;
#pragma unroll
        for (int r = 0; r < 4; r++)
          Fout[(size_t)(row0 + r) * EMBED + col] = acc[m][n][r] + bias;
      }
    }
  }
}

// ---------------- flash attention ----------------
// 512 blocks (XCD-swizzled) x 512 thr = 8 waves. Per wave: 16 q rows.
// QBLK=128/block. K/V tiles 64x64 bf16 double-buffered in LDS (XOR-swizzled
// via pre-swizzled global_load_lds source); 8 waves share one stage.
// Counted vmcnt(2). Softmax: DPP row_ror max-reduce (VALU, no DS), row-sum
// via mfma(P, ones) (matrix pipe, no DS), defer-rescale THR=8 (exp2 domain).
__global__ __launch_bounds__(512, 4) void flash_attn_kernel(
    const bf16* __restrict__ Qp, const bf16* __restrict__ Kp,
    const bf16* __restrict__ Vt, bf16* __restrict__ Op) {
  const int tid = threadIdx.x, lane = tid & 63, w = tid >> 6;
  const int g = lane >> 4, r15 = lane & 15;
  // bijective XCD swizzle: 512 blocks = 8 xcd * 64; chunk = 4 bh * 16 qt
  const int flat = blockIdx.x;
  const int c = (flat & 7) * 64 + (flat >> 3);
  const int bh = c >> 4, qt = c & 15;
  const int b = bh >> 4, h = bh & 15;

  __shared__ bf16 sK[2][4096];  // [buf][64 kv][64 d], swizzled
  __shared__ bf16 sV[2][4096];  // [buf][64 d][64 s], swizzled
  __shared__ bf16 sP[8][1024];  // per-wave [16 q][64 kv], swizzled

  const int strow = tid >> 3;         // 0..63 staging row
  const int stcolb = (tid & 7) << 4;  // staging col byte 0..112
  const int stsb = stcolb ^ ((strow & 7) << 4);

  const char* kgbase = (const char*)(Kp + ((size_t)b * SEQ) * EMBED + h * HD);
  const char* vgbase = (const char*)(Vt + (size_t)bh * HD * SEQ);

  auto stage = [&](int buf, int kv0) {
    gld_lds16((const bf16*)(kgbase + (size_t)(kv0 + strow) * (EMBED * 2) + stsb),
              &sK[buf][tid * 8]);
    gld_lds16((const bf16*)(vgbase + (size_t)strow * (SEQ * 2) + (size_t)kv0 * 2 + stsb),
              &sV[buf][tid * 8]);
  };

  stage(0, 0);

  // Q fragments: lane r15 holds q-row qbase+r15, k-slice g*8
  const int qbase = qt * 128 + w * 16;
  const bf16* qptr = Qp + ((size_t)(b * SEQ + qbase + r15)) * EMBED + h * HD;
  bf16x8 aq0 = *(const bf16x8*)(qptr + g * 8);
  bf16x8 aq1 = *(const bf16x8*)(qptr + 32 + g * 8);

  bf16x8 vones;
#pragma unroll
  for (int j = 0; j < 8; j++) vones[j] = (bf16)1.0f;

  f32x4 accv[4];
#pragma unroll
  for (int dt = 0; dt < 4; dt++) accv[dt] = (f32x4){0.f, 0.f, 0.f, 0.f};
  float mrow[4], lrow[4];
#pragma unroll
  for (int r = 0; r < 4; r++) { mrow[r] = -3.0e38f; lrow[r] = 0.f; }

  char* pbase = (char*)&sP[w][0];

  for (int it = 0; it < SEQ / 64; ++it) {
    const int cur = it & 1;
    if (it + 1 < SEQ / 64) {
      stage(cur ^ 1, (it + 1) * 64);
      asm volatile("s_waitcnt vmcnt(2)" ::: "memory");
    } else {
      asm volatile("s_waitcnt vmcnt(0)" ::: "memory");
    }
    __builtin_amdgcn_s_barrier();

    // ---- QK^T ----
    bf16x8 bk[4][2];
#pragma unroll
    for (int t = 0; t < 4; t++) {
      const int row = t * 16 + r15;
#pragma unroll
      for (int sl = 0; sl < 2; sl++) {
        const int off = (row * 128 + sl * 64 + g * 16) ^ ((row & 7) << 4);
        bk[t][sl] = *(const bf16x8*)((const char*)&sK[cur][0] + off);
      }
    }
    f32x4 sv[4];
    __builtin_amdgcn_s_setprio(1);
#pragma unroll
    for (int t = 0; t < 4; t++) {
      f32x4 z = (f32x4){0.f, 0.f, 0.f, 0.f};
      z = mfma16(aq0, bk[t][0], z);
      z = mfma16(aq1, bk[t][1], z);
      sv[t] = z;
    }
    __builtin_amdgcn_s_setprio(0);

    // V fragments early: DS work overlaps the VALU softmax below
    bf16x8 bv[4][2];
#pragma unroll
    for (int dt = 0; dt < 4; dt++) {
      const int row = dt * 16 + r15;
#pragma unroll
      for (int sl = 0; sl < 2; sl++) {
        const int off = (row * 128 + sl * 64 + g * 16) ^ ((row & 7) << 4);
        bv[dt][sl] = *(const bf16x8*)((const char*)&sV[cur][0] + off);
      }
    }

    // ---- online softmax (exp2 domain) ----
    float mt[4];
#pragma unroll
    for (int r = 0; r < 4; r++)
      mt[r] = fmaxf(fmaxf(sv[0][r], sv[1][r]), fmaxf(sv[2][r], sv[3][r]));
#pragma unroll
    for (int r = 0; r < 4; r++) {
      mt[r] = fmax_dpp<0x121>(mt[r]);  // row_ror:1
      mt[r] = fmax_dpp<0x122>(mt[r]);  // row_ror:2
      mt[r] = fmax_dpp<0x124>(mt[r]);  // row_ror:4
      mt[r] = fmax_dpp<0x128>(mt[r]);  // row_ror:8
    }
    bool grow = false;
#pragma unroll
    for (int r = 0; r < 4; r++) grow = grow || (mt[r] > mrow[r] + 8.f);
    if (__any(grow)) {
      f32x4 al;
#pragma unroll
      for (int r = 0; r < 4; r++) {
        const float mn = fmaxf(mrow[r], mt[r]);
        al[r] = fast_exp2(mrow[r] - mn);
        mrow[r] = mn;
        lrow[r] *= al[r];
      }
#pragma unroll
      for (int dt = 0; dt < 4; dt++) accv[dt] *= al;
    }
#pragma unroll
    for (int t = 0; t < 4; t++)
#pragma unroll
      for (int r = 0; r < 4; r++) {
        const float p = fast_exp2(sv[t][r] - mrow[r]);
        const int row = g * 4 + r;
        const int off = (row * 128 + (t * 16 + r15) * 2) ^ ((row & 7) << 4);
        *(bf16*)(pbase + off) = (bf16)p;
      }

    // ---- PV + row-sum via matrix pipe ----
    bf16x8 pa[2];
#pragma unroll
    for (int sl = 0; sl < 2; sl++) {
      const int off = (r15 * 128 + sl * 64 + g * 16) ^ ((r15 & 7) << 4);
      pa[sl] = *(const bf16x8*)(pbase + off);
    }
    __builtin_amdgcn_s_setprio(1);
    f32x4 ls = (f32x4){0.f, 0.f, 0.f, 0.f};
    ls = mfma16(pa[0], vones, ls);
    ls = mfma16(pa[1], vones, ls);
#pragma unroll
    for (int dt = 0; dt < 4; dt++) {
      accv[dt] = mfma16(pa[0], bv[dt][0], accv[dt]);
      accv[dt] = mfma16(pa[1], bv[dt][1], accv[dt]);
    }
    __builtin_amdgcn_s_setprio(0);
#pragma unroll
    for (int r = 0; r < 4; r++) lrow[r] += ls[r];
    __builtin_amdgcn_s_barrier();
  }

#pragma unroll
  for (int dt = 0; dt < 4; dt++)
#pragma unroll
    for (int r = 0; r < 4; r++) {
      const int row = qbase + g * 4 + r;
      const int col = h * HD + dt * 16 + r15;
      Op[((size_t)(b * SEQ + row)) * EMBED + col] = (bf16)(accv[dt][r] / lrow[r]);
    }
}

// ---------------- launch ----------------
extern "C" void kernel_launch(void* const* d_in, const int* in_sizes, int n_in,
                              void* d_out, int out_size, void* d_ws, size_t ws_size,
                              hipStream_t stream) {
  const float* x     = (const float*)d_in[0];
  const float* q_w   = (const float*)d_in[1];
  const float* q_b   = (const float*)d_in[2];
  const float* k_w   = (const float*)d_in[3];
  const float* k_b   = (const float*)d_in[4];
  const float* v_w   = (const float*)d_in[5];
  const float* v_b   = (const float*)d_in[6];
  const float* phase = (const float*)d_in[7];
  const float* ent   = (const float*)d_in[8];
  const float* out_w = (const float*)d_in[9];
  const float* out_b = (const float*)d_in[10];
  float* out = (float*)d_out;

  char* ws = (char*)d_ws;
  bf16* xb    = (bf16*)(ws + 0);          // 8388608 B, [B,S,E] bf16; reused as attn out
  bf16* wtall = (bf16*)(ws + 8388608);    // 6291456 B, [3072][1024] bf16 (Qeff|K|V)
  bf16* wot   = (bf16*)(ws + 14680064);   // 2097152 B, out_w^T bf16
  float* beff = (float*)(ws + 16777216);  // 4096 B
  bf16* Qp    = (bf16*)(ws + 16781312);   // 8388608 B
  bf16* Kp    = (bf16*)(ws + 25169920);   // 8388608 B
  bf16* Vt    = (bf16*)(ws + 33558528);   // 8388608 B, [b,h,d,s]
  (void)in_sizes; (void)n_in; (void)out_size; (void)ws_size;

  cvt_x_kernel<<<2048, 256, 0, stream>>>(x, xb, MTOK * EMBED / 4);
  transpose_wt_kernel<<<dim3(16, 16), 256, 0, stream>>>(k_w, wtall + 1024 * 1024);
  transpose_wt_kernel<<<dim3(16, 16), 256, 0, stream>>>(v_w, wtall + 2 * 1024 * 1024);
  transpose_wt_kernel<<<dim3(16, 16), 256, 0, stream>>>(out_w, wot);
  weff_kernel<<<dim3(16, 16), 256, 0, stream>>>(q_w, ent, phase, wtall);
  beff_kernel<<<16, 64, 0, stream>>>(q_b, ent, phase, beff);

  gemm_bt_kernel<0><<<dim3(32, 24), 256, 0, stream>>>(
      xb, wtall, beff, k_b, v_b, nullptr, Qp, Kp, Vt, nullptr);

  flash_attn_kernel<<<512, 512, 0, stream>>>(Qp, Kp, Vt, xb);

  gemm_bt_kernel<1><<<dim3(32, 8), 256, 0, stream>>>(
      xb, wot, nullptr, nullptr, nullptr, out_b, nullptr, nullptr, nullptr, out);
}

// Round 6
// 152.767 us; speedup vs baseline: 2.1560x; 1.1197x over previous
//
#include <hip/hip_runtime.h>
#include <hip/hip_bf16.h>

typedef __bf16 bf16;
typedef __bf16 bf16x8 __attribute__((ext_vector_type(8)));
typedef __bf16 bf16x4 __attribute__((ext_vector_type(4)));
typedef float f32x4 __attribute__((ext_vector_type(4)));
typedef unsigned int u32x2 __attribute__((ext_vector_type(2)));

#define EMBED 1024
#define NH 16
#define HD 64
#define BATCH 2
#define SEQ 2048
#define MTOK 4096
#define LOG2E 1.4426950408889634f

static __device__ __forceinline__ float fast_exp2(float x) {
#if __has_builtin(__builtin_amdgcn_exp2f)
  return __builtin_amdgcn_exp2f(x);
#else
  float r;
  asm("v_exp_f32 %0, %1" : "=v"(r) : "v"(x));
  return r;
#endif
}

// xor-16 max across lanes (VALU pipe, no DS)
static __device__ __forceinline__ float xor16_max(float x) {
#if __has_builtin(__builtin_amdgcn_permlane16_swap)
  u32x2 p = __builtin_amdgcn_permlane16_swap(__float_as_uint(x), __float_as_uint(x),
                                             false, false);
  return fmaxf(__uint_as_float(p.x), __uint_as_float(p.y));
#else
  int o = __builtin_amdgcn_ds_swizzle(__float_as_int(x), 0x401F);  // xor 16
  return fmaxf(x, __int_as_float(o));
#endif
}

// xor-32 max across lanes (VALU pipe, no DS)
static __device__ __forceinline__ float xor32_max(float x) {
#if __has_builtin(__builtin_amdgcn_permlane32_swap)
  u32x2 p = __builtin_amdgcn_permlane32_swap(__float_as_uint(x), __float_as_uint(x),
                                             false, false);
  return fmaxf(__uint_as_float(p.x), __uint_as_float(p.y));
#else
  return fmaxf(x, __shfl_xor(x, 32));
#endif
}

static __device__ __forceinline__ f32x4 mfma16(bf16x8 a, bf16x8 b, f32x4 c) {
  return __builtin_amdgcn_mfma_f32_16x16x32_bf16(a, b, c, 0, 0, 0);
}

static __device__ __forceinline__ void gld_lds16(const bf16* g, bf16* l) {
  __builtin_amdgcn_global_load_lds(
      (const __attribute__((address_space(1))) void*)g,
      (__attribute__((address_space(3))) void*)l, 16, 0, 0);
}

// ---------------- prep: x -> bf16 ----------------
__global__ __launch_bounds__(256) void cvt_x_kernel(const float* __restrict__ x,
                                                    bf16* __restrict__ xb, int n4) {
  int i = blockIdx.x * 256 + threadIdx.x;
  int stride = gridDim.x * 256;
  for (; i < n4; i += stride) {
    f32x4 v = ((const f32x4*)x)[i];
    bf16x4 o;
    o[0] = (bf16)v[0]; o[1] = (bf16)v[1]; o[2] = (bf16)v[2]; o[3] = (bf16)v[3];
    ((bf16x4*)xb)[i] = o;
  }
}

// ---------------- prep: W [K][N] fp32 -> Wt [N][K] bf16 ----------------
__global__ __launch_bounds__(256) void transpose_wt_kernel(const float* __restrict__ W,
                                                           bf16* __restrict__ Wt) {
  __shared__ float tile[64][65];
  const int bc = blockIdx.x * 64;  // n base
  const int br = blockIdx.y * 64;  // k base
  const int tid = threadIdx.x;
#pragma unroll
  for (int j = 0; j < 16; j++) {
    int idx = j * 256 + tid;
    int r = idx >> 6, c = idx & 63;
    tile[r][c] = W[(size_t)(br + r) * EMBED + bc + c];
  }
  __syncthreads();
#pragma unroll
  for (int j = 0; j < 16; j++) {
    int idx = j * 256 + tid;
    int r = idx >> 6, c = idx & 63;
    Wt[(size_t)(bc + r) * EMBED + br + c] = (bf16)tile[c][r];
  }
}

// ---------------- prep: W_q_eff^T = (q_w @ blockdiag(E')*log2e)^T, bf16 ----------------
// E'[h][d][e] = (ent[h][d][e] + (d==e) * cos(phase[h][d])^2 / 8) * LOG2E
__global__ __launch_bounds__(256) void weff_kernel(const float* __restrict__ qw,
                                                   const float* __restrict__ ent,
                                                   const float* __restrict__ phase,
                                                   bf16* __restrict__ WtQ) {
  __shared__ float qt[64][65];
  __shared__ float et[64][65];
  const int h = blockIdx.x;
  const int ibase = blockIdx.y * 64;
  const int tid = threadIdx.x;
#pragma unroll
  for (int j = 0; j < 16; j++) {
    int idx = j * 256 + tid;
    int i = idx >> 6, d = idx & 63;
    qt[i][d] = qw[(size_t)(ibase + i) * EMBED + h * HD + d];
  }
#pragma unroll
  for (int j = 0; j < 16; j++) {
    int idx = j * 256 + tid;
    int d = idx >> 6, e = idx & 63;
    float v = ent[((size_t)h * HD + d) * HD + e];
    if (d == e) { float cp = cosf(phase[h * HD + d]); v += cp * cp * 0.125f; }
    et[d][e] = v * LOG2E;
  }
  __syncthreads();
  const int i = tid & 63;
  const int e0 = (tid >> 6) * 16;
  float s[16];
#pragma unroll
  for (int ee = 0; ee < 16; ee++) s[ee] = 0.f;
  for (int d = 0; d < 64; d++) {
    float qv = qt[i][d];
#pragma unroll
    for (int ee = 0; ee < 16; ee++) s[ee] += qv * et[d][e0 + ee];
  }
#pragma unroll
  for (int ee = 0; ee < 16; ee++)
    WtQ[(size_t)(h * HD + e0 + ee) * EMBED + ibase + i] = (bf16)s[ee];
}

__global__ void beff_kernel(const float* __restrict__ qb, const float* __restrict__ ent,
                            const float* __restrict__ phase, float* __restrict__ beff) {
  const int h = blockIdx.x;
  const int e = threadIdx.x;  // 64
  float s = 0.f;
  for (int d = 0; d < 64; d++) {
    float v = ent[((size_t)h * HD + d) * HD + e];
    if (d == e) { float cp = cosf(phase[h * HD + d]); v += cp * cp * 0.125f; }
    s += qb[h * HD + d] * v;
  }
  beff[h * HD + e] = s * LOG2E;
}

// ---------------- GEMM: A[M][1024] bf16 x Bt[N][1024] bf16 ----------------
template <int EPI>
__global__ __launch_bounds__(256) void gemm_bt_kernel(
    const bf16* __restrict__ A, const bf16* __restrict__ Bt,
    const float* __restrict__ bias_q, const float* __restrict__ bias_k,
    const float* __restrict__ bias_v, const float* __restrict__ bias_o,
    bf16* __restrict__ Qp, bf16* __restrict__ Kp, bf16* __restrict__ Vt,
    float* __restrict__ Fout) {
  const int tid = threadIdx.x;
  const int lane = tid & 63, w = tid >> 6;
  const int g = lane >> 4, r15 = lane & 15;
  const int wr = w >> 1, wc = w & 1;
  const int bm = blockIdx.x * 128;
  const int bn = blockIdx.y * 128;

  __shared__ bf16 sA[128 * 32];
  __shared__ bf16 sB[128 * 32];

  f32x4 acc[4][4];
#pragma unroll
  for (int m = 0; m < 4; m++)
#pragma unroll
    for (int n = 0; n < 4; n++) acc[m][n] = (f32x4){0.f, 0.f, 0.f, 0.f};

  const int srow = tid >> 2;
  const int scol = (tid & 3) << 3;
  const bf16* aptr = A + (size_t)(bm + srow) * EMBED + scol;
  const bf16* bptr = Bt + (size_t)(bn + srow) * EMBED + scol;
  bf16* la = sA + tid * 8;
  bf16* lb = sB + tid * 8;

  for (int k0 = 0; k0 < EMBED; k0 += 32) {
    __syncthreads();
    gld_lds16(aptr + k0, la);
    gld_lds16(aptr + k0 + 64 * EMBED, la + 64 * 32);
    gld_lds16(bptr + k0, lb);
    gld_lds16(bptr + k0 + 64 * EMBED, lb + 64 * 32);
    __syncthreads();
    bf16x8 af[4], bfv[4];
#pragma unroll
    for (int m = 0; m < 4; m++)
      af[m] = *(const bf16x8*)&sA[(wr * 64 + m * 16 + r15) * 32 + g * 8];
#pragma unroll
    for (int n = 0; n < 4; n++)
      bfv[n] = *(const bf16x8*)&sB[(wc * 64 + n * 16 + r15) * 32 + g * 8];
#pragma unroll
    for (int m = 0; m < 4; m++)
#pragma unroll
      for (int n = 0; n < 4; n++) acc[m][n] = mfma16(af[m], bfv[n], acc[m][n]);
  }

  const int orow0 = bm + wr * 64;
  if (EPI == 0) {
    const int seg = bn >> 10;
    const int clb = (bn & 1023) + wc * 64;
#pragma unroll
    for (int n = 0; n < 4; n++) {
      const int cl = clb + n * 16 + r15;
      const float bias = (seg == 0) ? bias_q[cl] : (seg == 1) ? bias_k[cl] : bias_v[cl];
#pragma unroll
      for (int m = 0; m < 4; m++) {
        const int row0 = orow0 + m * 16 + g * 4;
        if (seg == 2) {
          const int b = row0 >> 11, s = row0 & 2047;
          const int hh = cl >> 6, d = cl & 63;
          bf16x4 pk;
#pragma unroll
          for (int r = 0; r < 4; r++) pk[r] = (bf16)(acc[m][n][r] + bias);
          *(bf16x4*)(Vt + ((size_t)((b * NH + hh) * HD + d)) * SEQ + s) = pk;
        } else {
          bf16* dst = ((seg == 0) ? Qp : Kp) + (size_t)row0 * EMBED + cl;
#pragma unroll
          for (int r = 0; r < 4; r++) dst[(size_t)r * EMBED] = (bf16)(acc[m][n][r] + bias);
        }
      }
    }
  } else {
    const int ocol0 = bn + wc * 64;
#pragma unroll
    for (int n = 0; n < 4; n++) {
      const int col = ocol0 + n * 16 + r15;
      const float bias = bias_o[col];
#pragma unroll
      for (int m = 0; m < 4; m++) {
        const int row0 = orow0 + m * 16 + g * 4;
#pragma unroll
        for (int r = 0; r < 4; r++)
          Fout[(size_t)(row0 + r) * EMBED + col] = acc[m][n][r] + bias;
      }
    }
  }
}

// ---------------- flash attention ----------------
// 512 blocks (XCD-swizzled) x 512 thr = 8 waves. Per wave: 16 q rows.
// SWAPPED QK^T: sv = mfma(K, Q) -> lane r15 owns q-row (qbase+r15) with 16
// k-values in registers. Softmax stats are per-lane scalars; max reduce is
// 15 fmax + permlane16/32 swaps (VALU only). P: 4 packed ds_write_b64 ->
// read back as PV's B-operand (2 ds_read_b128). Row-sum via mfma(ones, pb).
// K/V tiles 64x64 bf16 double-buffered in LDS, XOR-swizzled; counted vmcnt(2).
__global__ __launch_bounds__(512, 4) void flash_attn_kernel(
    const bf16* __restrict__ Qp, const bf16* __restrict__ Kp,
    const bf16* __restrict__ Vt, bf16* __restrict__ Op) {
  const int tid = threadIdx.x, lane = tid & 63, w = tid >> 6;
  const int g = lane >> 4, r15 = lane & 15;
  const int qq = r15 & 7;
  // bijective XCD swizzle: 512 blocks = 8 xcd * 64; chunk = 4 bh * 16 qt
  const int flat = blockIdx.x;
  const int c = (flat & 7) * 64 + (flat >> 3);
  const int bh = c >> 4, qt = c & 15;
  const int b = bh >> 4, h = bh & 15;

  __shared__ bf16 sK[2][4096];  // [buf][64 kv][64 d], swizzled
  __shared__ bf16 sV[2][4096];  // [buf][64 d][64 s], swizzled
  __shared__ bf16 sP[8][1024];  // per-wave [16 q][64 kv], swizzled

  const int strow = tid >> 3;         // 0..63 staging row
  const int stcolb = (tid & 7) << 4;  // staging col byte 0..112
  const int stsb = stcolb ^ ((strow & 7) << 4);

  const char* kgbase = (const char*)(Kp + ((size_t)b * SEQ) * EMBED + h * HD);
  const char* vgbase = (const char*)(Vt + (size_t)bh * HD * SEQ);

  auto stage = [&](int buf, int kv0) {
    gld_lds16((const bf16*)(kgbase + (size_t)(kv0 + strow) * (EMBED * 2) + stsb),
              &sK[buf][tid * 8]);
    gld_lds16((const bf16*)(vgbase + (size_t)strow * (SEQ * 2) + (size_t)kv0 * 2 + stsb),
              &sV[buf][tid * 8]);
  };

  stage(0, 0);

  // Q fragments (B-operand): lane r15 = q-col qbase+r15, depth slice g*8
  const int qbase = qt * 128 + w * 16;
  const bf16* qptr = Qp + ((size_t)(b * SEQ + qbase + r15)) * EMBED + h * HD;
  bf16x8 aq0 = *(const bf16x8*)(qptr + g * 8);
  bf16x8 aq1 = *(const bf16x8*)(qptr + 32 + g * 8);

  bf16x8 vones;
#pragma unroll
  for (int j = 0; j < 8; j++) vones[j] = (bf16)1.0f;

  // per-lane hoisted LDS byte offsets
  int kvoff[2];  // shared by bk (sK rows), bv (sV rows), pb (sP rows)
#pragma unroll
  for (int sl = 0; sl < 2; sl++)
    kvoff[sl] = r15 * 128 + ((sl * 64 + g * 16) ^ (qq << 4));
  int woff[4];  // P writes: row=r15, colbyte = t*32+8g
#pragma unroll
  for (int t = 0; t < 4; t++)
    woff[t] = r15 * 128 + ((t * 32 + 8 * g) ^ (qq << 4));

  f32x4 accv[4];
#pragma unroll
  for (int dt = 0; dt < 4; dt++) accv[dt] = (f32x4){0.f, 0.f, 0.f, 0.f};
  float mrow = -3.0e38f, lrow = 0.f;

  char* pbase = (char*)&sP[w][0];

  for (int it = 0; it < SEQ / 64; ++it) {
    const int cur = it & 1;
    if (it + 1 < SEQ / 64) {
      stage(cur ^ 1, (it + 1) * 64);
      asm volatile("s_waitcnt vmcnt(2)" ::: "memory");
    } else {
      asm volatile("s_waitcnt vmcnt(0)" ::: "memory");
    }
    __builtin_amdgcn_s_barrier();

    const char* kc = (const char*)&sK[cur][0];
    const char* vc = (const char*)&sV[cur][0];

    // ---- QK^T (swapped: A=K, B=Q) ----
    // sv[t][r] = S[q = qbase+r15][kv = t*16 + g*4 + r]
    f32x4 sv[4];
    __builtin_amdgcn_s_setprio(1);
#pragma unroll
    for (int t = 0; t < 4; t++) {
      bf16x8 bk0 = *(const bf16x8*)(kc + kvoff[0] + t * 2048);
      bf16x8 bk1 = *(const bf16x8*)(kc + kvoff[1] + t * 2048);
      f32x4 z = (f32x4){0.f, 0.f, 0.f, 0.f};
      z = mfma16(bk0, aq0, z);
      z = mfma16(bk1, aq1, z);
      sv[t] = z;
    }
    __builtin_amdgcn_s_setprio(0);

    // ---- per-lane softmax (exp2 domain) ----
    float mt = sv[0][0];
#pragma unroll
    for (int t = 0; t < 4; t++)
#pragma unroll
      for (int r = 0; r < 4; r++) mt = fmaxf(mt, sv[t][r]);
    mt = xor16_max(mt);
    mt = xor32_max(mt);

    if (__any(mt > mrow + 8.f)) {
      const float mn = fmaxf(mrow, mt);
      const float al = fast_exp2(mrow - mn);
      mrow = mn;
      lrow *= al;
#pragma unroll
      for (int dt = 0; dt < 4; dt++) accv[dt] *= al;
    }

    // P = exp2(S - mrow), packed bf16x4 per t -> LDS (4 x ds_write_b64)
#pragma unroll
    for (int t = 0; t < 4; t++) {
      bf16x4 pw;
#pragma unroll
      for (int r = 0; r < 4; r++) pw[r] = (bf16)fast_exp2(sv[t][r] - mrow);
      *(bf16x4*)(pbase + woff[t]) = pw;
    }

    // ---- PV (A = V^T, B = P) + row-sum via mfma(ones, pb) ----
    bf16x8 pb[2];
#pragma unroll
    for (int sl = 0; sl < 2; sl++)
      pb[sl] = *(const bf16x8*)(pbase + kvoff[sl]);

    __builtin_amdgcn_s_setprio(1);
    f32x4 ls = (f32x4){0.f, 0.f, 0.f, 0.f};
    ls = mfma16(vones, pb[0], ls);
    ls = mfma16(vones, pb[1], ls);
#pragma unroll
    for (int dt = 0; dt < 4; dt++) {
      bf16x8 bv0 = *(const bf16x8*)(vc + kvoff[0] + dt * 2048);
      bf16x8 bv1 = *(const bf16x8*)(vc + kvoff[1] + dt * 2048);
      accv[dt] = mfma16(bv0, pb[0], accv[dt]);
      accv[dt] = mfma16(bv1, pb[1], accv[dt]);
    }
    __builtin_amdgcn_s_setprio(0);
    lrow += ls[0];
    __builtin_amdgcn_s_barrier();
  }

  // accv[dt][r] = O^T[d = dt*16 + g*4 + r][q = qbase + r15]
  const float inv = 1.f / lrow;
  bf16* obase = Op + ((size_t)(b * SEQ + qbase + r15)) * EMBED + h * HD;
#pragma unroll
  for (int dt = 0; dt < 4; dt++) {
    bf16x4 o;
#pragma unroll
    for (int r = 0; r < 4; r++) o[r] = (bf16)(accv[dt][r] * inv);
    *(bf16x4*)(obase + dt * 16 + g * 4) = o;
  }
}

// ---------------- launch ----------------
extern "C" void kernel_launch(void* const* d_in, const int* in_sizes, int n_in,
                              void* d_out, int out_size, void* d_ws, size_t ws_size,
                              hipStream_t stream) {
  const float* x     = (const float*)d_in[0];
  const float* q_w   = (const float*)d_in[1];
  const float* q_b   = (const float*)d_in[2];
  const float* k_w   = (const float*)d_in[3];
  const float* k_b   = (const float*)d_in[4];
  const float* v_w   = (const float*)d_in[5];
  const float* v_b   = (const float*)d_in[6];
  const float* phase = (const float*)d_in[7];
  const float* ent   = (const float*)d_in[8];
  const float* out_w = (const float*)d_in[9];
  const float* out_b = (const float*)d_in[10];
  float* out = (float*)d_out;

  char* ws = (char*)d_ws;
  bf16* xb    = (bf16*)(ws + 0);          // 8388608 B, [B,S,E] bf16; reused as attn out
  bf16* wtall = (bf16*)(ws + 8388608);    // 6291456 B, [3072][1024] bf16 (Qeff|K|V)
  bf16* wot   = (bf16*)(ws + 14680064);   // 2097152 B, out_w^T bf16
  float* beff = (float*)(ws + 16777216);  // 4096 B
  bf16* Qp    = (bf16*)(ws + 16781312);   // 8388608 B
  bf16* Kp    = (bf16*)(ws + 25169920);   // 8388608 B
  bf16* Vt    = (bf16*)(ws + 33558528);   // 8388608 B, [b,h,d,s]
  (void)in_sizes; (void)n_in; (void)out_size; (void)ws_size;

  cvt_x_kernel<<<2048, 256, 0, stream>>>(x, xb, MTOK * EMBED / 4);
  transpose_wt_kernel<<<dim3(16, 16), 256, 0, stream>>>(k_w, wtall + 1024 * 1024);
  transpose_wt_kernel<<<dim3(16, 16), 256, 0, stream>>>(v_w, wtall + 2 * 1024 * 1024);
  transpose_wt_kernel<<<dim3(16, 16), 256, 0, stream>>>(out_w, wot);
  weff_kernel<<<dim3(16, 16), 256, 0, stream>>>(q_w, ent, phase, wtall);
  beff_kernel<<<16, 64, 0, stream>>>(q_b, ent, phase, beff);

  gemm_bt_kernel<0><<<dim3(32, 24), 256, 0, stream>>>(
      xb, wtall, beff, k_b, v_b, nullptr, Qp, Kp, Vt, nullptr);

  flash_attn_kernel<<<512, 512, 0, stream>>>(Qp, Kp, Vt, xb);

  gemm_bt_kernel<1><<<dim3(32, 8), 256, 0, stream>>>(
      xb, wot, nullptr, nullptr, nullptr, out_b, nullptr, nullptr, nullptr, out);
}

// Round 8
// 140.558 us; speedup vs baseline: 2.3433x; 1.0869x over previous
//
#include <hip/hip_runtime.h>
#include <hip/hip_bf16.h>

typedef __bf16 bf16;
typedef __bf16 bf16x8 __attribute__((ext_vector_type(8)));
typedef __bf16 bf16x4 __attribute__((ext_vector_type(4)));
typedef float f32x4 __attribute__((ext_vector_type(4)));
typedef float f32x16 __attribute__((ext_vector_type(16)));
typedef unsigned int u32x2 __attribute__((ext_vector_type(2)));

#define EMBED 1024
#define NH 16
#define HD 64
#define BATCH 2
#define SEQ 2048
#define MTOK 4096
#define LOG2E 1.4426950408889634f

static __device__ __forceinline__ float fast_exp2(float x) {
#if __has_builtin(__builtin_amdgcn_exp2f)
  return __builtin_amdgcn_exp2f(x);
#else
  float r;
  asm("v_exp_f32 %0, %1" : "=v"(r) : "v"(x));
  return r;
#endif
}

static __device__ __forceinline__ f32x4 mfma16(bf16x8 a, bf16x8 b, f32x4 c) {
  return __builtin_amdgcn_mfma_f32_16x16x32_bf16(a, b, c, 0, 0, 0);
}
static __device__ __forceinline__ f32x16 mfma32(bf16x8 a, bf16x8 b, f32x16 c) {
  return __builtin_amdgcn_mfma_f32_32x32x16_bf16(a, b, c, 0, 0, 0);
}

static __device__ __forceinline__ void gld_lds16(const bf16* g, bf16* l) {
  __builtin_amdgcn_global_load_lds(
      (const __attribute__((address_space(1))) void*)g,
      (__attribute__((address_space(3))) void*)l, 16, 0, 0);
}

// ---------------- fused prep ----------------
// blocks [0,2048): x->bf16 ; [2048,2304): k_w^T ; [2304,2560): v_w^T ;
// [2560,2816): out_w^T ; [2816,3072): weff ; [3072,3088): beff
__global__ __launch_bounds__(256) void prep_kernel(
    const float* __restrict__ x, const float* __restrict__ qw,
    const float* __restrict__ qb, const float* __restrict__ kw,
    const float* __restrict__ vw, const float* __restrict__ ow,
    const float* __restrict__ ent, const float* __restrict__ phase,
    bf16* __restrict__ xb, bf16* __restrict__ wtall, bf16* __restrict__ wot,
    float* __restrict__ beff) {
  __shared__ float t0[64][65];
  __shared__ float t1[64][65];
  const int bb = blockIdx.x;
  const int tid = threadIdx.x;

  if (bb < 2048) {  // cvt x
    const int n4 = MTOK * EMBED / 4;
    int i = bb * 256 + tid;
    for (; i < n4; i += 2048 * 256) {
      f32x4 v = ((const f32x4*)x)[i];
      bf16x4 o;
      o[0] = (bf16)v[0]; o[1] = (bf16)v[1]; o[2] = (bf16)v[2]; o[3] = (bf16)v[3];
      ((bf16x4*)xb)[i] = o;
    }
    return;
  }
  if (bb < 2816) {  // transposes
    const int idx = (bb - 2048) & 255;
    const float* W = (bb < 2304) ? kw : (bb < 2560) ? vw : ow;
    bf16* Wt = (bb < 2304) ? (wtall + 1024 * 1024)
             : (bb < 2560) ? (wtall + 2 * 1024 * 1024) : wot;
    const int bc = (idx & 15) * 64;
    const int br = (idx >> 4) * 64;
#pragma unroll
    for (int j = 0; j < 16; j++) {
      int id2 = j * 256 + tid;
      int r = id2 >> 6, c = id2 & 63;
      t0[r][c] = W[(size_t)(br + r) * EMBED + bc + c];
    }
    __syncthreads();
#pragma unroll
    for (int j = 0; j < 16; j++) {
      int id2 = j * 256 + tid;
      int r = id2 >> 6, c = id2 & 63;
      Wt[(size_t)(bc + r) * EMBED + br + c] = (bf16)t0[c][r];
    }
    return;
  }
  if (bb < 3072) {  // weff: W_q_eff^T = (q_w @ blockdiag(E')*log2e)^T
    const int idx = bb - 2816;
    const int h = idx >> 4;
    const int ibase = (idx & 15) * 64;
#pragma unroll
    for (int j = 0; j < 16; j++) {
      int id2 = j * 256 + tid;
      int i = id2 >> 6, d = id2 & 63;
      t0[i][d] = qw[(size_t)(ibase + i) * EMBED + h * HD + d];
    }
#pragma unroll
    for (int j = 0; j < 16; j++) {
      int id2 = j * 256 + tid;
      int d = id2 >> 6, e = id2 & 63;
      float v = ent[((size_t)h * HD + d) * HD + e];
      if (d == e) { float cp = cosf(phase[h * HD + d]); v += cp * cp * 0.125f; }
      t1[d][e] = v * LOG2E;
    }
    __syncthreads();
    const int i = tid & 63;
    const int e0 = (tid >> 6) * 16;
    float s[16];
#pragma unroll
    for (int ee = 0; ee < 16; ee++) s[ee] = 0.f;
    for (int d = 0; d < 64; d++) {
      float qv = t0[i][d];
#pragma unroll
      for (int ee = 0; ee < 16; ee++) s[ee] += qv * t1[d][e0 + ee];
    }
#pragma unroll
    for (int ee = 0; ee < 16; ee++)
      wtall[(size_t)(h * HD + e0 + ee) * EMBED + ibase + i] = (bf16)s[ee];
    return;
  }
  // beff
  const int h = bb - 3072;
  if (tid < 64) {
    const int e = tid;
    float s = 0.f;
    for (int d = 0; d < 64; d++) {
      float v = ent[((size_t)h * HD + d) * HD + e];
      if (d == e) { float cp = cosf(phase[h * HD + d]); v += cp * cp * 0.125f; }
      s += qb[h * HD + d] * v;
    }
    beff[h * HD + e] = s * LOG2E;
  }
}

// ---------------- GEMM: A[M][1024] bf16 x Bt[N][1024] bf16 ----------------
template <int EPI>
__global__ __launch_bounds__(256) void gemm_bt_kernel(
    const bf16* __restrict__ A, const bf16* __restrict__ Bt,
    const float* __restrict__ bias_q, const float* __restrict__ bias_k,
    const float* __restrict__ bias_v, const float* __restrict__ bias_o,
    bf16* __restrict__ Qp, bf16* __restrict__ Kp, bf16* __restrict__ Vt,
    float* __restrict__ Fout) {
  const int tid = threadIdx.x;
  const int lane = tid & 63, w = tid >> 6;
  const int g = lane >> 4, r15 = lane & 15;
  const int wr = w >> 1, wc = w & 1;
  const int bm = blockIdx.x * 128;
  const int bn = blockIdx.y * 128;

  __shared__ bf16 sA[128 * 32];
  __shared__ bf16 sB[128 * 32];

  f32x4 acc[4][4];
#pragma unroll
  for (int m = 0; m < 4; m++)
#pragma unroll
    for (int n = 0; n < 4; n++) acc[m][n] = (f32x4){0.f, 0.f, 0.f, 0.f};

  const int srow = tid >> 2;
  const int scol = (tid & 3) << 3;
  const bf16* aptr = A + (size_t)(bm + srow) * EMBED + scol;
  const bf16* bptr = Bt + (size_t)(bn + srow) * EMBED + scol;
  bf16* la = sA + tid * 8;
  bf16* lb = sB + tid * 8;

  for (int k0 = 0; k0 < EMBED; k0 += 32) {
    __syncthreads();
    gld_lds16(aptr + k0, la);
    gld_lds16(aptr + k0 + 64 * EMBED, la + 64 * 32);
    gld_lds16(bptr + k0, lb);
    gld_lds16(bptr + k0 + 64 * EMBED, lb + 64 * 32);
    __syncthreads();
    bf16x8 af[4], bfv[4];
#pragma unroll
    for (int m = 0; m < 4; m++)
      af[m] = *(const bf16x8*)&sA[(wr * 64 + m * 16 + r15) * 32 + g * 8];
#pragma unroll
    for (int n = 0; n < 4; n++)
      bfv[n] = *(const bf16x8*)&sB[(wc * 64 + n * 16 + r15) * 32 + g * 8];
#pragma unroll
    for (int m = 0; m < 4; m++)
#pragma unroll
      for (int n = 0; n < 4; n++) acc[m][n] = mfma16(af[m], bfv[n], acc[m][n]);
  }

  const int orow0 = bm + wr * 64;
  if (EPI == 0) {
    const int seg = bn >> 10;
    const int clb = (bn & 1023) + wc * 64;
#pragma unroll
    for (int n = 0; n < 4; n++) {
      const int cl = clb + n * 16 + r15;
      const float bias = (seg == 0) ? bias_q[cl] : (seg == 1) ? bias_k[cl] : bias_v[cl];
#pragma unroll
      for (int m = 0; m < 4; m++) {
        const int row0 = orow0 + m * 16 + g * 4;
        if (seg == 2) {
          const int b = row0 >> 11, s = row0 & 2047;
          const int hh = cl >> 6, d = cl & 63;
          bf16x4 pk;
#pragma unroll
          for (int r = 0; r < 4; r++) pk[r] = (bf16)(acc[m][n][r] + bias);
          *(bf16x4*)(Vt + ((size_t)((b * NH + hh) * HD + d)) * SEQ + s) = pk;
        } else {
          bf16* dst = ((seg == 0) ? Qp : Kp) + (size_t)row0 * EMBED + cl;
#pragma unroll
          for (int r = 0; r < 4; r++) dst[(size_t)r * EMBED] = (bf16)(acc[m][n][r] + bias);
        }
      }
    }
  } else {
    const int ocol0 = bn + wc * 64;
#pragma unroll
    for (int n = 0; n < 4; n++) {
      const int col = ocol0 + n * 16 + r15;
      const float bias = bias_o[col];
#pragma unroll
      for (int m = 0; m < 4; m++) {
        const int row0 = orow0 + m * 16 + g * 4;
#pragma unroll
        for (int r = 0; r < 4; r++)
          Fout[(size_t)(row0 + r) * EMBED + col] = acc[m][n][r] + bias;
      }
    }
  }
}

// ---------------- flash attention (32x32 MFMA, in-register P) ----------------
// 512 blocks (XCD-swizzled) x 256 thr = 4 waves. Per wave: 32 q rows.
// Swapped QK^T with mfma_32x32x16: S-acc lane layout col=q=lane&31,
// row=kv=(reg&3)+8*(reg>>2)+4*hi (+32 for tile1). P stays in registers:
// PV B-fragment dwords = {p0.x,p1.x,p0.y,p1.y} where
// p_d = permlane32_swap(qd[2kt].u[d], qd[2kt+1].u[d])  (verified derivation:
// hi=0 -> kv kt*16+0..7, hi=1 -> kv kt*16+8..15).
// Max/sum reduce: local chain + 1 permlane32_swap (sum = ss.x+ss.y).
// K/V tiles 64x64 bf16 double-buffered LDS, XOR-swizzled; counted vmcnt(4).
__global__ __launch_bounds__(256, 3) void flash_attn_kernel(
    const bf16* __restrict__ Qp, const bf16* __restrict__ Kp,
    const bf16* __restrict__ Vt, bf16* __restrict__ Op) {
  const int tid = threadIdx.x, lane = tid & 63, w = tid >> 6;
  const int q31 = lane & 31, hi = lane >> 5;
  // bijective XCD swizzle: 512 blocks = 8 xcd * 64; chunk = 4 bh * 16 qt
  const int flat = blockIdx.x;
  const int c = (flat & 7) * 64 + (flat >> 3);
  const int bh = c >> 4, qt = c & 15;
  const int b = bh >> 4, h = bh & 15;

  __shared__ bf16 sK[2][4096];  // [buf][64 kv][64 d], swizzled
  __shared__ bf16 sV[2][4096];  // [buf][64 d][64 s], swizzled

  const int strow = tid >> 3;         // 0..31 staging row
  const int stcolb = (tid & 7) << 4;  // staging col byte
  const int stsb = stcolb ^ ((strow & 7) << 4);

  const char* kgbase = (const char*)(Kp + ((size_t)b * SEQ) * EMBED + h * HD);
  const char* vgbase = (const char*)(Vt + (size_t)bh * HD * SEQ);

  auto stage = [&](int buf, int kv0) {
#pragma unroll
    for (int i = 0; i < 2; i++) {
      const int row = i * 32 + strow;
      gld_lds16((const bf16*)(kgbase + (size_t)(kv0 + row) * (EMBED * 2) + stsb),
                &sK[buf][i * 2048 + tid * 8]);
    }
#pragma unroll
    for (int i = 0; i < 2; i++) {
      const int row = i * 32 + strow;
      gld_lds16((const bf16*)(vgbase + (size_t)row * (SEQ * 2) + (size_t)kv0 * 2 + stsb),
                &sV[buf][i * 2048 + tid * 8]);
    }
  };

  stage(0, 0);

  // Q B-operand frags: lane q31 = q-col, k-slice hi*8 within each 16-depth
  const int qbase = qt * 128 + w * 32;
  const int qrow = qbase + q31;
  const bf16* qptr = Qp + ((size_t)(b * SEQ + qrow)) * EMBED + h * HD;
  bf16x8 aq[4];
#pragma unroll
  for (int ds = 0; ds < 4; ds++)
    aq[ds] = *(const bf16x8*)(qptr + ds * 16 + hi * 8);

  // per-lane swizzled column offsets (bytes): c[i] for col-chunk i*32 + hi*16
  const int sz = (q31 & 7) << 4;
  int cofs[4];
#pragma unroll
  for (int i = 0; i < 4; i++) cofs[i] = ((i * 32 + hi * 16) ^ sz);

  f32x16 o0, o1;
#pragma unroll
  for (int i = 0; i < 16; i++) { o0[i] = 0.f; o1[i] = 0.f; }
  float mrow = -3.0e38f, lrow = 0.f;

  for (int it = 0; it < SEQ / 64; ++it) {
    const int cur = it & 1;
    if (it + 1 < SEQ / 64) {
      stage(cur ^ 1, (it + 1) * 64);
      asm volatile("s_waitcnt vmcnt(4)" ::: "memory");
    } else {
      asm volatile("s_waitcnt vmcnt(0)" ::: "memory");
    }
    __builtin_amdgcn_s_barrier();

    const char* kc = (const char*)&sK[cur][0] + q31 * 128;
    const char* vc = (const char*)&sV[cur][0] + q31 * 128;

    // ---- QK^T: A = K (rows kv), B = Q -> S[kv][q] ----
    f32x16 s0, s1;
#pragma unroll
    for (int i = 0; i < 16; i++) { s0[i] = 0.f; s1[i] = 0.f; }
    __builtin_amdgcn_s_setprio(1);
#pragma unroll
    for (int ds = 0; ds < 4; ds++) {
      bf16x8 bk0 = *(const bf16x8*)(kc + cofs[ds]);
      bf16x8 bk1 = *(const bf16x8*)(kc + 4096 + cofs[ds]);
      s0 = mfma32(bk0, aq[ds], s0);
      s1 = mfma32(bk1, aq[ds], s1);
    }
    __builtin_amdgcn_s_setprio(0);

    // ---- per-lane softmax over the 32 held scores (exp2 domain) ----
    float mt = s0[0];
#pragma unroll
    for (int i = 1; i < 16; i++) mt = fmaxf(mt, s0[i]);
#pragma unroll
    for (int i = 0; i < 16; i++) mt = fmaxf(mt, s1[i]);
    {
      u32x2 sm = __builtin_amdgcn_permlane32_swap(__float_as_uint(mt),
                                                  __float_as_uint(mt), false, false);
      mt = fmaxf(__uint_as_float(sm.x), __uint_as_float(sm.y));
    }
    if (__any(mt > mrow + 8.f)) {
      const float mn = fmaxf(mrow, mt);
      const float al = fast_exp2(mrow - mn);
      mrow = mn;
      lrow *= al;
      o0 *= al;
      o1 *= al;
    }

    // P = exp2(S - mrow): pack into 8 quads (bf16x4 = 2 dwords each)
    union B4 { bf16x4 v; unsigned int u[2]; };
    B4 qd[8];
    float lsum = 0.f;
#pragma unroll
    for (int j = 0; j < 4; j++)
#pragma unroll
      for (int r = 0; r < 4; r++) {
        float pv = fast_exp2(s0[4 * j + r] - mrow);
        lsum += pv;
        qd[j].v[r] = (bf16)pv;
      }
#pragma unroll
    for (int j = 0; j < 4; j++)
#pragma unroll
      for (int r = 0; r < 4; r++) {
        float pv = fast_exp2(s1[4 * j + r] - mrow);
        lsum += pv;
        qd[4 + j].v[r] = (bf16)pv;
      }
    {
      u32x2 ss = __builtin_amdgcn_permlane32_swap(__float_as_uint(lsum),
                                                  __float_as_uint(lsum), false, false);
      lrow += __uint_as_float(ss.x) + __uint_as_float(ss.y);  // own + partner
    }

    // assemble PV B-fragments: frag[kt] covers kv = kt*16 .. +15
    bf16x8 pfrag[4];
#pragma unroll
    for (int kt = 0; kt < 4; kt++) {
      u32x2 p0 = __builtin_amdgcn_permlane32_swap(qd[2 * kt].u[0],
                                                  qd[2 * kt + 1].u[0], false, false);
      u32x2 p1 = __builtin_amdgcn_permlane32_swap(qd[2 * kt].u[1],
                                                  qd[2 * kt + 1].u[1], false, false);
      union { unsigned int u[4]; bf16x8 v; } f;
      f.u[0] = p0.x; f.u[1] = p1.x; f.u[2] = p0.y; f.u[3] = p1.y;
      pfrag[kt] = f.v;
    }

    // ---- PV: A = V^T (rows d), B = P -> O[d][q] ----
    __builtin_amdgcn_s_setprio(1);
#pragma unroll
    for (int kt = 0; kt < 4; kt++) {
      bf16x8 av0 = *(const bf16x8*)(vc + cofs[kt]);
      bf16x8 av1 = *(const bf16x8*)(vc + 4096 + cofs[kt]);
      o0 = mfma32(av0, pfrag[kt], o0);
      o1 = mfma32(av1, pfrag[kt], o1);
    }
    __builtin_amdgcn_s_setprio(0);
    __builtin_amdgcn_s_barrier();
  }

  // O[d][q]: lane q31 owns q-col; d = dt*32 + 8*j + 4*hi + r
  const float inv = 1.f / lrow;
  bf16* obase = Op + ((size_t)(b * SEQ + qrow)) * EMBED + h * HD;
#pragma unroll
  for (int j = 0; j < 4; j++) {
    bf16x4 st;
#pragma unroll
    for (int r = 0; r < 4; r++) st[r] = (bf16)(o0[4 * j + r] * inv);
    *(bf16x4*)(obase + 8 * j + 4 * hi) = st;
  }
#pragma unroll
  for (int j = 0; j < 4; j++) {
    bf16x4 st;
#pragma unroll
    for (int r = 0; r < 4; r++) st[r] = (bf16)(o1[4 * j + r] * inv);
    *(bf16x4*)(obase + 32 + 8 * j + 4 * hi) = st;
  }
}

// ---------------- launch ----------------
extern "C" void kernel_launch(void* const* d_in, const int* in_sizes, int n_in,
                              void* d_out, int out_size, void* d_ws, size_t ws_size,
                              hipStream_t stream) {
  const float* x     = (const float*)d_in[0];
  const float* q_w   = (const float*)d_in[1];
  const float* q_b   = (const float*)d_in[2];
  const float* k_w   = (const float*)d_in[3];
  const float* k_b   = (const float*)d_in[4];
  const float* v_w   = (const float*)d_in[5];
  const float* v_b   = (const float*)d_in[6];
  const float* phase = (const float*)d_in[7];
  const float* ent   = (const float*)d_in[8];
  const float* out_w = (const float*)d_in[9];
  const float* out_b = (const float*)d_in[10];
  float* out = (float*)d_out;

  char* ws = (char*)d_ws;
  bf16* xb    = (bf16*)(ws + 0);          // 8388608 B, [B,S,E] bf16; reused as attn out
  bf16* wtall = (bf16*)(ws + 8388608);    // 6291456 B, [3072][1024] bf16 (Qeff|K|V)
  bf16* wot   = (bf16*)(ws + 14680064);   // 2097152 B, out_w^T bf16
  float* beff = (float*)(ws + 16777216);  // 4096 B
  bf16* Qp    = (bf16*)(ws + 16781312);   // 8388608 B
  bf16* Kp    = (bf16*)(ws + 25169920);   // 8388608 B
  bf16* Vt    = (bf16*)(ws + 33558528);   // 8388608 B, [b,h,d,s]
  (void)in_sizes; (void)n_in; (void)out_size; (void)ws_size;

  prep_kernel<<<3088, 256, 0, stream>>>(x, q_w, q_b, k_w, v_w, out_w, ent, phase,
                                        xb, wtall, wot, beff);

  gemm_bt_kernel<0><<<dim3(32, 24), 256, 0, stream>>>(
      xb, wtall, beff, k_b, v_b, nullptr, Qp, Kp, Vt, nullptr);

  flash_attn_kernel<<<512, 256, 0, stream>>>(Qp, Kp, Vt, xb);

  gemm_bt_kernel<1><<<dim3(32, 8), 256, 0, stream>>>(
      xb, wot, nullptr, nullptr, nullptr, out_b, nullptr, nullptr, nullptr, out);
}

// Round 9
// 136.932 us; speedup vs baseline: 2.4054x; 1.0265x over previous
//
#include <hip/hip_runtime.h>
#include <hip/hip_bf16.h>

typedef __bf16 bf16;
typedef __bf16 bf16x8 __attribute__((ext_vector_type(8)));
typedef __bf16 bf16x4 __attribute__((ext_vector_type(4)));
typedef float f32x4 __attribute__((ext_vector_type(4)));
typedef float f32x16 __attribute__((ext_vector_type(16)));
typedef unsigned int u32x2 __attribute__((ext_vector_type(2)));

#define EMBED 1024
#define NH 16
#define HD 64
#define BATCH 2
#define SEQ 2048
#define MTOK 4096
#define LOG2E 1.4426950408889634f

static __device__ __forceinline__ float fast_exp2(float x) {
#if __has_builtin(__builtin_amdgcn_exp2f)
  return __builtin_amdgcn_exp2f(x);
#else
  float r;
  asm("v_exp_f32 %0, %1" : "=v"(r) : "v"(x));
  return r;
#endif
}

static __device__ __forceinline__ f32x4 mfma16(bf16x8 a, bf16x8 b, f32x4 c) {
  return __builtin_amdgcn_mfma_f32_16x16x32_bf16(a, b, c, 0, 0, 0);
}
static __device__ __forceinline__ f32x16 mfma32(bf16x8 a, bf16x8 b, f32x16 c) {
  return __builtin_amdgcn_mfma_f32_32x32x16_bf16(a, b, c, 0, 0, 0);
}

static __device__ __forceinline__ void gld_lds16(const bf16* g, bf16* l) {
  __builtin_amdgcn_global_load_lds(
      (const __attribute__((address_space(1))) void*)g,
      (__attribute__((address_space(3))) void*)l, 16, 0, 0);
}

// ---------------- fused prep ----------------
// blocks [0,2048): x->bf16 ; [2048,2304): k_w^T ; [2304,2560): v_w^T ;
// [2560,2816): out_w^T ; [2816,3072): weff ; [3072,3088): beff
__global__ __launch_bounds__(256) void prep_kernel(
    const float* __restrict__ x, const float* __restrict__ qw,
    const float* __restrict__ qb, const float* __restrict__ kw,
    const float* __restrict__ vw, const float* __restrict__ ow,
    const float* __restrict__ ent, const float* __restrict__ phase,
    bf16* __restrict__ xb, bf16* __restrict__ wtall, bf16* __restrict__ wot,
    float* __restrict__ beff) {
  __shared__ float t0[64][65];
  __shared__ float t1[64][65];
  const int bb = blockIdx.x;
  const int tid = threadIdx.x;

  if (bb < 2048) {  // cvt x
    const int n4 = MTOK * EMBED / 4;
    int i = bb * 256 + tid;
    for (; i < n4; i += 2048 * 256) {
      f32x4 v = ((const f32x4*)x)[i];
      bf16x4 o;
      o[0] = (bf16)v[0]; o[1] = (bf16)v[1]; o[2] = (bf16)v[2]; o[3] = (bf16)v[3];
      ((bf16x4*)xb)[i] = o;
    }
    return;
  }
  if (bb < 2816) {  // transposes
    const int idx = (bb - 2048) & 255;
    const float* W = (bb < 2304) ? kw : (bb < 2560) ? vw : ow;
    bf16* Wt = (bb < 2304) ? (wtall + 1024 * 1024)
             : (bb < 2560) ? (wtall + 2 * 1024 * 1024) : wot;
    const int bc = (idx & 15) * 64;
    const int br = (idx >> 4) * 64;
#pragma unroll
    for (int j = 0; j < 16; j++) {
      int id2 = j * 256 + tid;
      int r = id2 >> 6, c = id2 & 63;
      t0[r][c] = W[(size_t)(br + r) * EMBED + bc + c];
    }
    __syncthreads();
#pragma unroll
    for (int j = 0; j < 16; j++) {
      int id2 = j * 256 + tid;
      int r = id2 >> 6, c = id2 & 63;
      Wt[(size_t)(bc + r) * EMBED + br + c] = (bf16)t0[c][r];
    }
    return;
  }
  if (bb < 3072) {  // weff: W_q_eff^T = (q_w @ blockdiag(E')*log2e)^T
    const int idx = bb - 2816;
    const int h = idx >> 4;
    const int ibase = (idx & 15) * 64;
#pragma unroll
    for (int j = 0; j < 16; j++) {
      int id2 = j * 256 + tid;
      int i = id2 >> 6, d = id2 & 63;
      t0[i][d] = qw[(size_t)(ibase + i) * EMBED + h * HD + d];
    }
#pragma unroll
    for (int j = 0; j < 16; j++) {
      int id2 = j * 256 + tid;
      int d = id2 >> 6, e = id2 & 63;
      float v = ent[((size_t)h * HD + d) * HD + e];
      if (d == e) { float cp = cosf(phase[h * HD + d]); v += cp * cp * 0.125f; }
      t1[d][e] = v * LOG2E;
    }
    __syncthreads();
    const int i = tid & 63;
    const int e0 = (tid >> 6) * 16;
    float s[16];
#pragma unroll
    for (int ee = 0; ee < 16; ee++) s[ee] = 0.f;
    for (int d = 0; d < 64; d++) {
      float qv = t0[i][d];
#pragma unroll
      for (int ee = 0; ee < 16; ee++) s[ee] += qv * t1[d][e0 + ee];
    }
#pragma unroll
    for (int ee = 0; ee < 16; ee++)
      wtall[(size_t)(h * HD + e0 + ee) * EMBED + ibase + i] = (bf16)s[ee];
    return;
  }
  // beff
  const int h = bb - 3072;
  if (tid < 64) {
    const int e = tid;
    float s = 0.f;
    for (int d = 0; d < 64; d++) {
      float v = ent[((size_t)h * HD + d) * HD + e];
      if (d == e) { float cp = cosf(phase[h * HD + d]); v += cp * cp * 0.125f; }
      s += qb[h * HD + d] * v;
    }
    beff[h * HD + e] = s * LOG2E;
  }
}

// ---------------- GEMM: A[M][1024] bf16 x Bt[N][1024] bf16 ----------------
template <int EPI>
__global__ __launch_bounds__(256) void gemm_bt_kernel(
    const bf16* __restrict__ A, const bf16* __restrict__ Bt,
    const float* __restrict__ bias_q, const float* __restrict__ bias_k,
    const float* __restrict__ bias_v, const float* __restrict__ bias_o,
    bf16* __restrict__ Qp, bf16* __restrict__ Kp, bf16* __restrict__ Vt,
    float* __restrict__ Fout) {
  const int tid = threadIdx.x;
  const int lane = tid & 63, w = tid >> 6;
  const int g = lane >> 4, r15 = lane & 15;
  const int wr = w >> 1, wc = w & 1;
  const int bm = blockIdx.x * 128;
  const int bn = blockIdx.y * 128;

  __shared__ bf16 sA[128 * 32];
  __shared__ bf16 sB[128 * 32];

  f32x4 acc[4][4];
#pragma unroll
  for (int m = 0; m < 4; m++)
#pragma unroll
    for (int n = 0; n < 4; n++) acc[m][n] = (f32x4){0.f, 0.f, 0.f, 0.f};

  const int srow = tid >> 2;
  const int scol = (tid & 3) << 3;
  const bf16* aptr = A + (size_t)(bm + srow) * EMBED + scol;
  const bf16* bptr = Bt + (size_t)(bn + srow) * EMBED + scol;
  bf16* la = sA + tid * 8;
  bf16* lb = sB + tid * 8;

  for (int k0 = 0; k0 < EMBED; k0 += 32) {
    __syncthreads();
    gld_lds16(aptr + k0, la);
    gld_lds16(aptr + k0 + 64 * EMBED, la + 64 * 32);
    gld_lds16(bptr + k0, lb);
    gld_lds16(bptr + k0 + 64 * EMBED, lb + 64 * 32);
    __syncthreads();
    bf16x8 af[4], bfv[4];
#pragma unroll
    for (int m = 0; m < 4; m++)
      af[m] = *(const bf16x8*)&sA[(wr * 64 + m * 16 + r15) * 32 + g * 8];
#pragma unroll
    for (int n = 0; n < 4; n++)
      bfv[n] = *(const bf16x8*)&sB[(wc * 64 + n * 16 + r15) * 32 + g * 8];
#pragma unroll
    for (int m = 0; m < 4; m++)
#pragma unroll
      for (int n = 0; n < 4; n++) acc[m][n] = mfma16(af[m], bfv[n], acc[m][n]);
  }

  const int orow0 = bm + wr * 64;
  if (EPI == 0) {
    const int seg = bn >> 10;
    const int clb = (bn & 1023) + wc * 64;
#pragma unroll
    for (int n = 0; n < 4; n++) {
      const int cl = clb + n * 16 + r15;
      const float bias = (seg == 0) ? bias_q[cl] : (seg == 1) ? bias_k[cl] : bias_v[cl];
#pragma unroll
      for (int m = 0; m < 4; m++) {
        const int row0 = orow0 + m * 16 + g * 4;
        if (seg == 2) {
          const int b = row0 >> 11, s = row0 & 2047;
          const int hh = cl >> 6, d = cl & 63;
          bf16x4 pk;
#pragma unroll
          for (int r = 0; r < 4; r++) pk[r] = (bf16)(acc[m][n][r] + bias);
          *(bf16x4*)(Vt + ((size_t)((b * NH + hh) * HD + d)) * SEQ + s) = pk;
        } else {
          bf16* dst = ((seg == 0) ? Qp : Kp) + (size_t)row0 * EMBED + cl;
#pragma unroll
          for (int r = 0; r < 4; r++) dst[(size_t)r * EMBED] = (bf16)(acc[m][n][r] + bias);
        }
      }
    }
  } else {
    const int ocol0 = bn + wc * 64;
#pragma unroll
    for (int n = 0; n < 4; n++) {
      const int col = ocol0 + n * 16 + r15;
      const float bias = bias_o[col];
#pragma unroll
      for (int m = 0; m < 4; m++) {
        const int row0 = orow0 + m * 16 + g * 4;
#pragma unroll
        for (int r = 0; r < 4; r++)
          Fout[(size_t)(row0 + r) * EMBED + col] = acc[m][n][r] + bias;
      }
    }
  }
}

// ---------------- flash attention (32x32 MFMA, in-register P, KVBLK=128) ----
// 512 blocks (XCD-swizzled) x 256 thr = 4 waves. Per wave: 32 q rows.
// 2-deep KV pipeline: 128 kv staged per iter (16 iters), all 32 QK MFMAs
// issue before one 64-score softmax, then 8 pfrags + 16 PV MFMAs. Counted
// vmcnt(8) keeps next tile's 8 gld_lds in flight across the barrier.
__global__ __launch_bounds__(256, 2) void flash_attn_kernel(
    const bf16* __restrict__ Qp, const bf16* __restrict__ Kp,
    const bf16* __restrict__ Vt, bf16* __restrict__ Op) {
  const int tid = threadIdx.x, lane = tid & 63, w = tid >> 6;
  const int q31 = lane & 31, hi = lane >> 5;
  // bijective XCD swizzle: 512 blocks = 8 xcd * 64; chunk = 4 bh * 16 qt
  const int flat = blockIdx.x;
  const int c = (flat & 7) * 64 + (flat >> 3);
  const int bh = c >> 4, qt = c & 15;
  const int b = bh >> 4, h = bh & 15;

  __shared__ bf16 sK[2][8192];  // [buf][128 kv][64 d] (rows 128B), swizzled
  __shared__ bf16 sV[2][8192];  // [buf][64 d][128 s] (rows 256B), swizzled

  // K staging: 4 rounds x 32 rows, 8 thr/row x 16B
  const int strow = tid >> 3;
  const int stsb = ((tid & 7) << 4) ^ ((strow & 7) << 4);
  // V staging: 4 rounds x 16 rows, 16 thr/row x 16B
  const int svrow = tid >> 4;
  const int svsb = ((tid & 15) << 4) ^ ((svrow & 7) << 4);

  const char* kgbase = (const char*)(Kp + ((size_t)b * SEQ) * EMBED + h * HD);
  const char* vgbase = (const char*)(Vt + (size_t)bh * HD * SEQ);

  auto stage = [&](int buf, int kv0) {
#pragma unroll
    for (int i = 0; i < 4; i++) {
      const int row = i * 32 + strow;
      gld_lds16((const bf16*)(kgbase + (size_t)(kv0 + row) * (EMBED * 2) + stsb),
                &sK[buf][i * 2048 + tid * 8]);
    }
#pragma unroll
    for (int i = 0; i < 4; i++) {
      const int row = i * 16 + svrow;
      gld_lds16((const bf16*)(vgbase + (size_t)row * (SEQ * 2) + (size_t)kv0 * 2 + svsb),
                &sV[buf][i * 2048 + tid * 8]);
    }
  };

  stage(0, 0);

  // Q B-operand frags: lane q31 = q-col, k-slice hi*8 within each 16-depth
  const int qbase = qt * 128 + w * 32;
  const int qrow = qbase + q31;
  const bf16* qptr = Qp + ((size_t)(b * SEQ + qrow)) * EMBED + h * HD;
  bf16x8 aq[4];
#pragma unroll
  for (int ds = 0; ds < 4; ds++)
    aq[ds] = *(const bf16x8*)(qptr + ds * 16 + hi * 8);

  const int sz = (q31 & 7) << 4;
  // K read col offsets (row len 128B): d-chunk ds*32 + hi*16
  int cofs[4];
#pragma unroll
  for (int i = 0; i < 4; i++) cofs[i] = ((i * 32 + hi * 16) ^ sz);
  // V read col offsets (row len 256B): kv-chunk kt*32 + hi*16, kt=0..7
  int vofs[8];
#pragma unroll
  for (int i = 0; i < 8; i++) vofs[i] = ((i * 32 + hi * 16) ^ sz);

  f32x16 o0, o1;
#pragma unroll
  for (int i = 0; i < 16; i++) { o0[i] = 0.f; o1[i] = 0.f; }
  float mrow = -3.0e38f, lrow = 0.f;

  for (int it = 0; it < SEQ / 128; ++it) {
    const int cur = it & 1;
    if (it + 1 < SEQ / 128) {
      stage(cur ^ 1, (it + 1) * 128);
      asm volatile("s_waitcnt vmcnt(8)" ::: "memory");
    } else {
      asm volatile("s_waitcnt vmcnt(0)" ::: "memory");
    }
    __builtin_amdgcn_s_barrier();

    const char* kc = (const char*)&sK[cur][0] + q31 * 128;
    const char* vc = (const char*)&sV[cur][0] + q31 * 256;

    // ---- QK^T: A = K rows kv (4 x 32-kv tiles), B = Q -> S[kv][q] ----
    f32x16 s0, s1, s2, s3;
#pragma unroll
    for (int i = 0; i < 16; i++) { s0[i] = 0.f; s1[i] = 0.f; s2[i] = 0.f; s3[i] = 0.f; }
    __builtin_amdgcn_s_setprio(1);
#pragma unroll
    for (int ds = 0; ds < 4; ds++) {
      bf16x8 bk0 = *(const bf16x8*)(kc + cofs[ds]);
      bf16x8 bk1 = *(const bf16x8*)(kc + 4096 + cofs[ds]);
      bf16x8 bk2 = *(const bf16x8*)(kc + 8192 + cofs[ds]);
      bf16x8 bk3 = *(const bf16x8*)(kc + 12288 + cofs[ds]);
      s0 = mfma32(bk0, aq[ds], s0);
      s1 = mfma32(bk1, aq[ds], s1);
      s2 = mfma32(bk2, aq[ds], s2);
      s3 = mfma32(bk3, aq[ds], s3);
    }
    __builtin_amdgcn_s_setprio(0);

    // ---- per-lane softmax over 64 held scores (exp2 domain) ----
    float mt = s0[0];
#pragma unroll
    for (int i = 1; i < 16; i++) mt = fmaxf(mt, s0[i]);
#pragma unroll
    for (int i = 0; i < 16; i++) mt = fmaxf(mt, fmaxf(s1[i], fmaxf(s2[i], s3[i])));
    {
      u32x2 sm = __builtin_amdgcn_permlane32_swap(__float_as_uint(mt),
                                                  __float_as_uint(mt), false, false);
      mt = fmaxf(__uint_as_float(sm.x), __uint_as_float(sm.y));
    }
    if (__any(mt > mrow + 8.f)) {
      const float mn = fmaxf(mrow, mt);
      const float al = fast_exp2(mrow - mn);
      mrow = mn;
      lrow *= al;
      o0 *= al;
      o1 *= al;
    }

    // P = exp2(S - mrow): 16 quads; qd[t*4+j].v[r] covers kv=32t+8j+4hi+r
    union B4 { bf16x4 v; unsigned int u[2]; };
    B4 qd[16];
    float lsum = 0.f;
#pragma unroll
    for (int j = 0; j < 4; j++)
#pragma unroll
      for (int r = 0; r < 4; r++) {
        float pv = fast_exp2(s0[4 * j + r] - mrow);
        lsum += pv; qd[j].v[r] = (bf16)pv;
      }
#pragma unroll
    for (int j = 0; j < 4; j++)
#pragma unroll
      for (int r = 0; r < 4; r++) {
        float pv = fast_exp2(s1[4 * j + r] - mrow);
        lsum += pv; qd[4 + j].v[r] = (bf16)pv;
      }
#pragma unroll
    for (int j = 0; j < 4; j++)
#pragma unroll
      for (int r = 0; r < 4; r++) {
        float pv = fast_exp2(s2[4 * j + r] - mrow);
        lsum += pv; qd[8 + j].v[r] = (bf16)pv;
      }
#pragma unroll
    for (int j = 0; j < 4; j++)
#pragma unroll
      for (int r = 0; r < 4; r++) {
        float pv = fast_exp2(s3[4 * j + r] - mrow);
        lsum += pv; qd[12 + j].v[r] = (bf16)pv;
      }
    {
      u32x2 ss = __builtin_amdgcn_permlane32_swap(__float_as_uint(lsum),
                                                  __float_as_uint(lsum), false, false);
      lrow += __uint_as_float(ss.x) + __uint_as_float(ss.y);  // own + partner
    }

    // assemble PV B-fragments: pfrag[kt] covers kv = kt*16 .. +15 (kt=0..7)
    bf16x8 pfrag[8];
#pragma unroll
    for (int kt = 0; kt < 8; kt++) {
      u32x2 p0 = __builtin_amdgcn_permlane32_swap(qd[2 * kt].u[0],
                                                  qd[2 * kt + 1].u[0], false, false);
      u32x2 p1 = __builtin_amdgcn_permlane32_swap(qd[2 * kt].u[1],
                                                  qd[2 * kt + 1].u[1], false, false);
      union { unsigned int u[4]; bf16x8 v; } f;
      f.u[0] = p0.x; f.u[1] = p1.x; f.u[2] = p0.y; f.u[3] = p1.y;
      pfrag[kt] = f.v;
    }

    // ---- PV: A = V^T (rows d), B = P -> O[d][q] ----
    __builtin_amdgcn_s_setprio(1);
#pragma unroll
    for (int kt = 0; kt < 8; kt++) {
      bf16x8 av0 = *(const bf16x8*)(vc + vofs[kt]);
      bf16x8 av1 = *(const bf16x8*)(vc + 8192 + vofs[kt]);
      o0 = mfma32(av0, pfrag[kt], o0);
      o1 = mfma32(av1, pfrag[kt], o1);
    }
    __builtin_amdgcn_s_setprio(0);
    __builtin_amdgcn_s_barrier();
  }

  // O[d][q]: lane q31 owns q-col; d = dt*32 + 8*j + 4*hi + r
  const float inv = 1.f / lrow;
  bf16* obase = Op + ((size_t)(b * SEQ + qrow)) * EMBED + h * HD;
#pragma unroll
  for (int j = 0; j < 4; j++) {
    bf16x4 st;
#pragma unroll
    for (int r = 0; r < 4; r++) st[r] = (bf16)(o0[4 * j + r] * inv);
    *(bf16x4*)(obase + 8 * j + 4 * hi) = st;
  }
#pragma unroll
  for (int j = 0; j < 4; j++) {
    bf16x4 st;
#pragma unroll
    for (int r = 0; r < 4; r++) st[r] = (bf16)(o1[4 * j + r] * inv);
    *(bf16x4*)(obase + 32 + 8 * j + 4 * hi) = st;
  }
}

// ---------------- launch ----------------
extern "C" void kernel_launch(void* const* d_in, const int* in_sizes, int n_in,
                              void* d_out, int out_size, void* d_ws, size_t ws_size,
                              hipStream_t stream) {
  const float* x     = (const float*)d_in[0];
  const float* q_w   = (const float*)d_in[1];
  const float* q_b   = (const float*)d_in[2];
  const float* k_w   = (const float*)d_in[3];
  const float* k_b   = (const float*)d_in[4];
  const float* v_w   = (const float*)d_in[5];
  const float* v_b   = (const float*)d_in[6];
  const float* phase = (const float*)d_in[7];
  const float* ent   = (const float*)d_in[8];
  const float* out_w = (const float*)d_in[9];
  const float* out_b = (const float*)d_in[10];
  float* out = (float*)d_out;

  char* ws = (char*)d_ws;
  bf16* xb    = (bf16*)(ws + 0);          // 8388608 B, [B,S,E] bf16; reused as attn out
  bf16* wtall = (bf16*)(ws + 8388608);    // 6291456 B, [3072][1024] bf16 (Qeff|K|V)
  bf16* wot   = (bf16*)(ws + 14680064);   // 2097152 B, out_w^T bf16
  float* beff = (float*)(ws + 16777216);  // 4096 B
  bf16* Qp    = (bf16*)(ws + 16781312);   // 8388608 B
  bf16* Kp    = (bf16*)(ws + 25169920);   // 8388608 B
  bf16* Vt    = (bf16*)(ws + 33558528);   // 8388608 B, [b,h,d,s]
  (void)in_sizes; (void)n_in; (void)out_size; (void)ws_size;

  prep_kernel<<<3088, 256, 0, stream>>>(x, q_w, q_b, k_w, v_w, out_w, ent, phase,
                                        xb, wtall, wot, beff);

  gemm_bt_kernel<0><<<dim3(32, 24), 256, 0, stream>>>(
      xb, wtall, beff, k_b, v_b, nullptr, Qp, Kp, Vt, nullptr);

  flash_attn_kernel<<<512, 256, 0, stream>>>(Qp, Kp, Vt, xb);

  gemm_bt_kernel<1><<<dim3(32, 8), 256, 0, stream>>>(
      xb, wot, nullptr, nullptr, nullptr, out_b, nullptr, nullptr, nullptr, out);
}